// Round 5
// baseline (875.288 us; speedup 1.0000x reference)
//
#include <hip/hip_runtime.h>
#include <math.h>

// GAT 2-layer: N=100K nodes, E=1.6M edges + self loops.
// Round-5 change: CSR-by-dst build replaced by 2-pass bucketed binning.
//   Round-4 counters: fill_kernel 130us, WRITE_SIZE=108MB = tot*64B -> each
//   scattered 4B col write dirtied a full line (16x amplification).
//   binA appends edges to 782 bucket tails (L2-resident partial lines,
//   ~6.8MB writes); binB builds per-bucket CSR in a 12KB window per WG.
//   offs[] are bucket-local (gaps between buckets) - agg only needs per-node
//   contiguity. count/scan/fill kernels deleted.
// Aggregation: wave per node, flash-style online softmax, bf16 feature
// gathers (round-3/4: halved agg1 fetch), fp32 accumulate.

#define NPB   128          // nodes per bucket (dst>>7)
#define BCAP  3072         // bucket capacity (mean ~2176, 19 sigma margin)

__device__ __forceinline__ float wave_max(float v){
  #pragma unroll
  for (int m = 1; m < 64; m <<= 1) v = fmaxf(v, __shfl_xor(v, m));
  return v;
}
__device__ __forceinline__ float wave_sum(float v){
  #pragma unroll
  for (int m = 1; m < 64; m <<= 1) v += __shfl_xor(v, m);
  return v;
}
// wave-internal LDS write->read ordering (no cross-wave sync needed)
__device__ __forceinline__ void lds_fence(){
  asm volatile("s_waitcnt lgkmcnt(0)" ::: "memory");
  __builtin_amdgcn_sched_barrier(0);
}

// bf16 helpers (RNE pack, shift unpack)
__device__ __forceinline__ unsigned short f2bf(float f){
  unsigned int u = __float_as_uint(f);
  u += 0x7FFFu + ((u >> 16) & 1u);
  return (unsigned short)(u >> 16);
}
__device__ __forceinline__ float bf2f(unsigned short b){
  return __uint_as_float(((unsigned int)b) << 16);
}
__device__ __forceinline__ float2 bfpair(unsigned int u){
  float2 r;
  r.x = __uint_as_float(u << 16);
  r.y = __uint_as_float(u & 0xFFFF0000u);
  return r;
}

// ---------------- CSR build: bucketed binning ----------------

__global__ void zero_bcnt_kernel(int* __restrict__ p, int nb){
  int i = blockIdx.x * 256 + threadIdx.x;
  if (i < nb) p[i] = 0;
}

// pass A: append packed (src | local_dst<<17) to bucket dst>>7
__global__ void binA_kernel(const int* __restrict__ src, const int* __restrict__ dst,
                            int* __restrict__ bcnt, unsigned int* __restrict__ bdata,
                            int E, int tot){
  int i = blockIdx.x * 256 + threadIdx.x;
  if (i >= tot) return;
  int s, d;
  if (i < E){ s = src[i]; d = dst[i]; } else { s = i - E; d = s; }
  int b = d >> 7;
  int pos = atomicAdd(&bcnt[b], 1);
  if (pos < BCAP)
    bdata[(size_t)b * BCAP + pos] = (unsigned int)s | ((unsigned int)(d & 127) << 17);
}

// pass B: per-bucket histogram -> prefix -> offs/cnt -> scatter col locally
__global__ __launch_bounds__(256)
void binB_kernel(const int* __restrict__ bcnt, const unsigned int* __restrict__ bdata,
                 int* __restrict__ offs, int* __restrict__ cntg,
                 int* __restrict__ col, int n){
  __shared__ int hist[NPB];
  __shared__ int sc[NPB];
  __shared__ int curp[NPB];
  int tid = threadIdx.x;
  int b = blockIdx.x;
  int base_node = b * NPB;
  int cb = bcnt[b]; if (cb > BCAP) cb = BCAP;
  size_t bb = (size_t)b * BCAP;

  if (tid < NPB) hist[tid] = 0;
  __syncthreads();
  for (int j = tid; j < cb; j += 256){
    unsigned int u = bdata[bb + j];
    atomicAdd(&hist[u >> 17], 1);
  }
  __syncthreads();
  if (tid < NPB) sc[tid] = hist[tid];
  __syncthreads();
  #pragma unroll
  for (int d1 = 1; d1 < NPB; d1 <<= 1){
    int v = 0;
    if (tid < NPB && tid >= d1) v = sc[tid - d1];
    __syncthreads();
    if (tid < NPB) sc[tid] += v;
    __syncthreads();
  }
  if (tid < NPB){
    int ex = tid ? sc[tid - 1] : 0;      // exclusive prefix
    int node = base_node + tid;
    if (node < n){
      offs[node] = (int)bb + ex;
      cntg[node] = hist[tid];
    }
    curp[tid] = ex;
  }
  __syncthreads();
  for (int j = tid; j < cb; j += 256){
    unsigned int u = bdata[bb + j];
    int r = atomicAdd(&curp[u >> 17], 1);
    col[bb + r] = (int)(u & 0x1FFFFu);
  }
}

// ---------------- GEMM1: [n,128]fp32 @ [128,128]fp32 -> bf16 ----------------
__global__ __launch_bounds__(256)
void gemm1_kernel(const float* __restrict__ X, const float* __restrict__ W,
                  unsigned short* __restrict__ Hb, int n){
  __shared__ float xs[16][132];   // transposed: xs[k][row]
  __shared__ float ws[16][128];
  int tid = threadIdx.x;
  int rg = tid >> 4, cg = tid & 15;
  int r0 = rg * 8, c0 = cg * 4;
  int row0 = blockIdx.x * 128;
  float acc[8][8];
  #pragma unroll
  for (int i = 0; i < 8; i++)
    #pragma unroll
    for (int j = 0; j < 8; j++) acc[i][j] = 0.f;

  for (int k0 = 0; k0 < 128; k0 += 16){
    #pragma unroll
    for (int l = 0; l < 2; l++){
      int f4 = tid + l * 256;
      int kk = f4 >> 5, cq = f4 & 31;
      float4 w = *(const float4*)(W + (size_t)(k0 + kk) * 128 + cq * 4);
      *(float4*)&ws[kk][cq * 4] = w;
    }
    #pragma unroll
    for (int l = 0; l < 2; l++){
      int f4 = tid + l * 256;
      int row = f4 >> 2, kq = f4 & 3;
      float4 v = make_float4(0.f, 0.f, 0.f, 0.f);
      if (row0 + row < n)
        v = *(const float4*)(X + (size_t)(row0 + row) * 128 + k0 + kq * 4);
      xs[kq*4+0][row] = v.x; xs[kq*4+1][row] = v.y;
      xs[kq*4+2][row] = v.z; xs[kq*4+3][row] = v.w;
    }
    __syncthreads();
    #pragma unroll
    for (int k = 0; k < 16; k++){
      float4 xa = *(const float4*)&xs[k][r0];
      float4 xb = *(const float4*)&xs[k][r0 + 4];
      float4 wa = *(const float4*)&ws[k][c0];
      float4 wb = *(const float4*)&ws[k][c0 + 64];
      float xr[8] = {xa.x,xa.y,xa.z,xa.w,xb.x,xb.y,xb.z,xb.w};
      float wr[8] = {wa.x,wa.y,wa.z,wa.w,wb.x,wb.y,wb.z,wb.w};
      #pragma unroll
      for (int i = 0; i < 8; i++)
        #pragma unroll
        for (int j = 0; j < 8; j++)
          acc[i][j] = fmaf(xr[i], wr[j], acc[i][j]);
    }
    __syncthreads();
  }
  #pragma unroll
  for (int i = 0; i < 8; i++){
    int r = row0 + r0 + i;
    if (r < n){
      ushort4 a4, b4;
      a4.x = f2bf(acc[i][0]); a4.y = f2bf(acc[i][1]);
      a4.z = f2bf(acc[i][2]); a4.w = f2bf(acc[i][3]);
      b4.x = f2bf(acc[i][4]); b4.y = f2bf(acc[i][5]);
      b4.z = f2bf(acc[i][6]); b4.w = f2bf(acc[i][7]);
      *(ushort4*)(Hb + (size_t)r * 128 + c0)      = a4;
      *(ushort4*)(Hb + (size_t)r * 128 + c0 + 64) = b4;
    }
  }
}

// ---------------- att1: bf16 input ----------------
__global__ __launch_bounds__(256)
void att1_kernel(const unsigned short* __restrict__ Hb, const float* __restrict__ As,
                 const float* __restrict__ Ad, float* __restrict__ asrc,
                 float* __restrict__ adst, int n){
  __shared__ float sa[128], sd[128];
  int tid = threadIdx.x;
  if (tid < 128){ sa[tid] = As[tid]; sd[tid] = Ad[tid]; }
  __syncthreads();
  int t = blockIdx.x * 256 + tid;
  if (t >= n * 8) return;
  int node = t >> 3, h = t & 7;
  const uint4* hp = (const uint4*)(Hb + (size_t)node * 128 + h * 16);
  uint4 u0 = hp[0], u1 = hp[1];
  unsigned int w[8] = {u0.x,u0.y,u0.z,u0.w,u1.x,u1.y,u1.z,u1.w};
  float s = 0.f, d = 0.f;
  #pragma unroll
  for (int q = 0; q < 8; q++){
    float2 p = bfpair(w[q]);
    s = fmaf(p.x, sa[h*16 + 2*q],     s);
    s = fmaf(p.y, sa[h*16 + 2*q + 1], s);
    d = fmaf(p.x, sd[h*16 + 2*q],     d);
    d = fmaf(p.y, sd[h*16 + 2*q + 1], d);
  }
  asrc[t] = s; adst[t] = d;
}

// ---------------- agg1: wave per node, 8 heads x 16 ch, bf16 gather --------
#define CAP1 64
__global__ __launch_bounds__(256)
void agg1_kernel(const unsigned short* __restrict__ Hb, const int* __restrict__ offs,
                 const int* __restrict__ cnt, const int* __restrict__ col,
                 const float* __restrict__ asrc, const float* __restrict__ adst,
                 const float* __restrict__ bias, float* __restrict__ G, int n){
  __shared__ int   scol[4][CAP1];
  __shared__ float sex[4][CAP1][8];
  int lane = threadIdx.x & 63;
  int wid  = threadIdx.x >> 6;
  int node = blockIdx.x * 4 + wid;
  if (node >= n) return;
  int beg = offs[node], deg = cnt[node];

  int hA = lane & 7, iA = lane >> 3;
  int hB = lane >> 3;
  float adA = adst[node * 8 + hA];

  float2 acc = make_float2(0.f, 0.f);
  float m_run = -INFINITY;
  float denomA = 0.f;   // per-lane partial (head hA), rescaled per chunk

  for (int c0 = 0; c0 < deg; c0 += CAP1){
    int cdeg = min(CAP1, deg - c0);
    // phase A: logits in registers (static idx), chunk max per head
    float ev[8];
    float cm = -INFINITY;
    #pragma unroll
    for (int k = 0; k < 8; k++){
      int i = iA + k * 8;
      ev[k] = -INFINITY;
      if (i < cdeg){
        int s = col[beg + c0 + i];
        if (hA == 0) scol[wid][i] = s;
        float e = asrc[s * 8 + hA] + adA;
        e = e > 0.f ? e : 0.2f * e;
        ev[k] = e;
        cm = fmaxf(cm, e);
      }
    }
    cm = fmaxf(cm, __shfl_xor(cm, 8));
    cm = fmaxf(cm, __shfl_xor(cm, 16));
    cm = fmaxf(cm, __shfl_xor(cm, 32));
    float m_new = fmaxf(m_run, cm);
    float scaleA = __expf(m_run - m_new);   // first chunk: exp(-inf)=0
    denomA *= scaleA;
    #pragma unroll
    for (int k = 0; k < 8; k++){
      int i = iA + k * 8;
      if (i < cdeg){
        float ex = __expf(ev[k] - m_new);
        denomA += ex;
        sex[wid][i][hA] = ex;
      }
    }
    m_run = m_new;
    float scaleB = __shfl(scaleA, hB);
    acc.x *= scaleB; acc.y *= scaleB;
    lds_fence();
    // phase C: gather bf16 rows (4B/lane), unrolled x8 for MLP
    const unsigned int* Hu = (const unsigned int*)Hb;
    int i = 0;
    for (; i + 7 < cdeg; i += 8){
      int ss[8]; float xx[8]; unsigned int uu[8];
      #pragma unroll
      for (int k = 0; k < 8; k++){
        ss[k] = scol[wid][i + k];
        xx[k] = sex[wid][i + k][hB];
      }
      #pragma unroll
      for (int k = 0; k < 8; k++)
        uu[k] = Hu[(size_t)ss[k] * 64 + lane];
      #pragma unroll
      for (int k = 0; k < 8; k++){
        float2 f = bfpair(uu[k]);
        acc.x = fmaf(xx[k], f.x, acc.x);
        acc.y = fmaf(xx[k], f.y, acc.y);
      }
    }
    for (; i < cdeg; i++){
      int s = scol[wid][i];
      float x = sex[wid][i][hB];
      float2 f = bfpair(Hu[(size_t)s * 64 + lane]);
      acc.x = fmaf(x, f.x, acc.x);
      acc.y = fmaf(x, f.y, acc.y);
    }
  }
  denomA += __shfl_xor(denomA, 8);
  denomA += __shfl_xor(denomA, 16);
  denomA += __shfl_xor(denomA, 32);
  float denomB = __shfl(denomA, hB) + 1e-16f;
  float2 bv = ((const float2*)bias)[lane];
  float ox = acc.x / denomB + bv.x;
  float oy = acc.y / denomB + bv.y;
  ox = ox > 0.f ? ox : expm1f(ox);   // ELU
  oy = oy > 0.f ? oy : expm1f(oy);
  ((float2*)G)[(size_t)node * 64 + lane] = make_float2(ox, oy);
}

// ---------------- GEMM2: [n,128]fp32 @ [128,40] -> bf16 ----------------
__global__ __launch_bounds__(256)
void gemm2_kernel(const float* __restrict__ X, const float* __restrict__ W,
                  unsigned short* __restrict__ Hb, int n){
  __shared__ float xs[16][132];
  __shared__ float ws[16][48];
  int tid = threadIdx.x;
  int rg = tid >> 3, cg = tid & 7;
  int r0 = rg * 4, c0 = cg * 6;
  int row0 = blockIdx.x * 128;
  float acc[4][6];
  #pragma unroll
  for (int i = 0; i < 4; i++)
    #pragma unroll
    for (int j = 0; j < 6; j++) acc[i][j] = 0.f;

  for (int k0 = 0; k0 < 128; k0 += 16){
    #pragma unroll
    for (int l = 0; l < 3; l++){
      int idx = tid + l * 256;
      int kk = idx / 48, c = idx % 48;
      ws[kk][c] = (c < 40) ? W[(size_t)(k0 + kk) * 40 + c] : 0.f;
    }
    #pragma unroll
    for (int l = 0; l < 2; l++){
      int f4 = tid + l * 256;
      int row = f4 >> 2, kq = f4 & 3;
      float4 v = make_float4(0.f, 0.f, 0.f, 0.f);
      if (row0 + row < n)
        v = *(const float4*)(X + (size_t)(row0 + row) * 128 + k0 + kq * 4);
      xs[kq*4+0][row] = v.x; xs[kq*4+1][row] = v.y;
      xs[kq*4+2][row] = v.z; xs[kq*4+3][row] = v.w;
    }
    __syncthreads();
    #pragma unroll
    for (int k = 0; k < 16; k++){
      float4 xa = *(const float4*)&xs[k][r0];
      float xr[4] = {xa.x, xa.y, xa.z, xa.w};
      float wr[6];
      #pragma unroll
      for (int j = 0; j < 6; j++) wr[j] = ws[k][c0 + j];
      #pragma unroll
      for (int i = 0; i < 4; i++)
        #pragma unroll
        for (int j = 0; j < 6; j++)
          acc[i][j] = fmaf(xr[i], wr[j], acc[i][j]);
    }
    __syncthreads();
  }
  #pragma unroll
  for (int i = 0; i < 4; i++){
    int r = row0 + r0 + i;
    if (r < n){
      #pragma unroll
      for (int j = 0; j < 6; j++){
        int c = c0 + j;
        if (c < 40) Hb[(size_t)r * 40 + c] = f2bf(acc[i][j]);
      }
    }
  }
}

// ---------------- att2: bf16 input ----------------
__global__ __launch_bounds__(256)
void att2_kernel(const unsigned short* __restrict__ Hb, const float* __restrict__ As,
                 const float* __restrict__ Ad, float* __restrict__ asrc,
                 float* __restrict__ adst, int n){
  int lane = threadIdx.x & 63;
  int node = blockIdx.x * 4 + (threadIdx.x >> 6);
  if (node >= n) return;
  float v = 0.f, a = 0.f, d = 0.f;
  if (lane < 40){
    v = bf2f(Hb[(size_t)node * 40 + lane]);
    a = As[lane];
    d = Ad[lane];
  }
  float s1 = wave_sum(v * a);
  float s2 = wave_sum(v * d);
  if (lane == 0){ asrc[node] = s1; adst[node] = s2; }
}

// ---------------- agg2 + bias + log_softmax, bf16 gather ----------------
#define CAP2 128
__global__ __launch_bounds__(256)
void agg2_kernel(const unsigned short* __restrict__ Hb, const int* __restrict__ offs,
                 const int* __restrict__ cnt, const int* __restrict__ col,
                 const float* __restrict__ asrc, const float* __restrict__ adst,
                 const float* __restrict__ bias, float* __restrict__ out, int n){
  __shared__ int   scol[4][CAP2];
  __shared__ float sex[4][CAP2];
  int lane = threadIdx.x & 63;
  int wid  = threadIdx.x >> 6;
  int node = blockIdx.x * 4 + wid;
  if (node >= n) return;
  int beg = offs[node], deg = cnt[node];
  float ad = adst[node];

  float acc = 0.f;
  float m_run = -INFINITY;
  float denom = 0.f;

  for (int c0 = 0; c0 < deg; c0 += CAP2){
    int cdeg = min(CAP2, deg - c0);
    float ev[2];
    float cm = -INFINITY;
    #pragma unroll
    for (int k = 0; k < 2; k++){
      int i = lane + k * 64;
      ev[k] = -INFINITY;
      if (i < cdeg){
        int s = col[beg + c0 + i];
        scol[wid][i] = s;
        float e = asrc[s] + ad;
        e = e > 0.f ? e : 0.2f * e;
        ev[k] = e;
        cm = fmaxf(cm, e);
      }
    }
    cm = wave_max(cm);
    float m_new = fmaxf(m_run, cm);
    float scale = __expf(m_run - m_new);
    float part = 0.f;
    #pragma unroll
    for (int k = 0; k < 2; k++){
      int i = lane + k * 64;
      if (i < cdeg){
        float ex = __expf(ev[k] - m_new);
        part += ex;
        sex[wid][i] = ex;
      }
    }
    denom = denom * scale + wave_sum(part);
    acc *= scale;
    m_run = m_new;
    lds_fence();
    int i = 0;
    for (; i + 7 < cdeg; i += 8){
      int ss[8]; float xx[8]; float ff[8];
      #pragma unroll
      for (int k = 0; k < 8; k++){
        ss[k] = scol[wid][i + k];
        xx[k] = sex[wid][i + k];
      }
      #pragma unroll
      for (int k = 0; k < 8; k++)
        ff[k] = (lane < 40) ? bf2f(Hb[(size_t)ss[k] * 40 + lane]) : 0.f;
      #pragma unroll
      for (int k = 0; k < 8; k++)
        acc = fmaf(xx[k], ff[k], acc);
    }
    for (; i < cdeg; i++){
      int s = scol[wid][i];
      float x = sex[wid][i];
      float f = (lane < 40) ? bf2f(Hb[(size_t)s * 40 + lane]) : 0.f;
      acc = fmaf(x, f, acc);
    }
  }
  float val = 0.f;
  if (lane < 40) val = acc / (denom + 1e-16f) + bias[lane];

  float mx = wave_max(lane < 40 ? val : -INFINITY);
  float ssum = wave_sum(lane < 40 ? __expf(val - mx) : 0.f);
  float ls = logf(ssum);
  if (lane < 40) out[(size_t)node * 40 + lane] = val - mx - ls;
}

// ---------------- launch ----------------
extern "C" void kernel_launch(void* const* d_in, const int* in_sizes, int n_in,
                              void* d_out, int out_size, void* d_ws, size_t ws_size,
                              hipStream_t stream){
  const float* x   = (const float*)d_in[0];
  const int*   ei  = (const int*)d_in[1];
  const float* W1  = (const float*)d_in[2];
  const float* as1 = (const float*)d_in[3];
  const float* ad1 = (const float*)d_in[4];
  const float* b1  = (const float*)d_in[5];
  const float* W2  = (const float*)d_in[6];
  const float* as2 = (const float*)d_in[7];
  const float* ad2 = (const float*)d_in[8];
  const float* b2  = (const float*)d_in[9];
  float* out = (float*)d_out;

  int n = in_sizes[0] / 128;
  int E = in_sizes[1] / 2;
  const int* src = ei;
  const int* dst = ei + E;
  int tot = E + n;
  int nb = (n + NPB - 1) / NPB;       // buckets

  char* w = (char*)d_ws;
  size_t off = 0;
  auto alloc = [&](size_t bytes){
    size_t r = off; off += (bytes + 255) & ~(size_t)255; return r;
  };
  int* bcnt = (int*)(w + alloc((size_t)nb * 4));
  unsigned int* bdata = (unsigned int*)(w + alloc((size_t)nb * BCAP * 4));
  int* offs = (int*)(w + alloc((size_t)n * 4));
  int* cnt  = (int*)(w + alloc((size_t)n * 4));
  int* col  = (int*)(w + alloc((size_t)nb * BCAP * 4));
  unsigned short* h1b = (unsigned short*)(w + alloc((size_t)n * 128 * 2));
  float* g1   = (float*)(w + alloc((size_t)n * 128 * 4));
  float* s1   = (float*)(w + alloc((size_t)n * 8 * 4));
  float* t1   = (float*)(w + alloc((size_t)n * 8 * 4));
  unsigned short* h2b = h1b;   // layer-2 aliases (h1b dead after agg1)
  float* s2 = s1;
  float* t2 = t1;
  (void)ws_size; (void)n_in; (void)out_size;

  zero_bcnt_kernel<<<(nb + 255) / 256, 256, 0, stream>>>(bcnt, nb);
  binA_kernel<<<(tot + 255) / 256, 256, 0, stream>>>(src, dst, bcnt, bdata, E, tot);
  binB_kernel<<<nb, 256, 0, stream>>>(bcnt, bdata, offs, cnt, col, n);

  gemm1_kernel<<<(n + 127) / 128, 256, 0, stream>>>(x, W1, h1b, n);
  att1_kernel<<<(n * 8 + 255) / 256, 256, 0, stream>>>(h1b, as1, ad1, s1, t1, n);
  agg1_kernel<<<(n + 3) / 4, 256, 0, stream>>>(h1b, offs, cnt, col, s1, t1, b1, g1, n);

  gemm2_kernel<<<(n + 127) / 128, 256, 0, stream>>>(g1, W2, h2b, n);
  att2_kernel<<<(n + 3) / 4, 256, 0, stream>>>(h2b, as2, ad2, s2, t2, n);
  agg2_kernel<<<(n + 3) / 4, 256, 0, stream>>>(h2b, offs, cnt, col, s2, t2, b2, out, n);
}

// Round 6
// 546.324 us; speedup vs baseline: 1.6021x; 1.6021x over previous
//
#include <hip/hip_runtime.h>
#include <math.h>

// GAT 2-layer: N=100K nodes, E=1.6M edges + self loops.
// CSR build: bucketed binning with XCD-privatized counters.
//   Round-5 counters: binA 437us, VALUBusy 0.2%, 188GB/s -> pure same-address
//   atomic serialization (2176 atomics/counter x ~200ns cross-XCD round trip).
//   Fix: 3125 buckets (dst>>5) x 8 replicas keyed by blockIdx&7 (~XCD id on
//   MI355X round-robin dispatch) -> chain length 68, counter lines XCD-local.
//   binB merges the 8 replica lists per bucket; col writes stay in a 6KB
//   per-WG window (round-4's 108MB write amplification stays fixed).
// Aggregation: wave per node, flash-style online softmax, bf16 feature
// gathers (round-4: halved agg1 fetch), fp32 accumulate.

#define NPB   32           // nodes per bucket (dst>>5)
#define G     8            // counter replicas (~per-XCD via blockIdx&7)
#define RCAP  192          // capacity per (bucket,replica): mean 68+selfloops
#define BSTRIDE (G*RCAP)   // col entries per bucket

__device__ __forceinline__ float wave_max(float v){
  #pragma unroll
  for (int m = 1; m < 64; m <<= 1) v = fmaxf(v, __shfl_xor(v, m));
  return v;
}
__device__ __forceinline__ float wave_sum(float v){
  #pragma unroll
  for (int m = 1; m < 64; m <<= 1) v += __shfl_xor(v, m);
  return v;
}
// wave-internal LDS write->read ordering (no cross-wave sync needed)
__device__ __forceinline__ void lds_fence(){
  asm volatile("s_waitcnt lgkmcnt(0)" ::: "memory");
  __builtin_amdgcn_sched_barrier(0);
}

// bf16 helpers (RNE pack, shift unpack)
__device__ __forceinline__ unsigned short f2bf(float f){
  unsigned int u = __float_as_uint(f);
  u += 0x7FFFu + ((u >> 16) & 1u);
  return (unsigned short)(u >> 16);
}
__device__ __forceinline__ float bf2f(unsigned short b){
  return __uint_as_float(((unsigned int)b) << 16);
}
__device__ __forceinline__ float2 bfpair(unsigned int u){
  float2 r;
  r.x = __uint_as_float(u << 16);
  r.y = __uint_as_float(u & 0xFFFF0000u);
  return r;
}

// ---------------- CSR build: bucketed binning ----------------

__global__ void zero_bcnt_kernel(int* __restrict__ p, int nr){
  int i = blockIdx.x * 256 + threadIdx.x;
  if (i < nr) p[i] = 0;
}

// pass A: append packed (src | local_dst<<17) to replica (dst>>5, blockIdx&7)
__global__ void binA_kernel(const int* __restrict__ src, const int* __restrict__ dst,
                            int* __restrict__ bcnt, unsigned int* __restrict__ bdata,
                            int E, int tot){
  int i = blockIdx.x * 256 + threadIdx.x;
  if (i >= tot) return;
  int s, d;
  if (i < E){ s = src[i]; d = dst[i]; } else { s = i - E; d = s; }
  int b = d >> 5;
  int r = b * G + (blockIdx.x & (G - 1));
  int pos = atomicAdd(&bcnt[r], 1);
  if (pos < RCAP)
    bdata[(size_t)r * RCAP + pos] = (unsigned int)s | ((unsigned int)(d & 31) << 17);
}

// pass B: merge replicas -> histogram -> prefix -> offs/cnt -> local scatter
__global__ __launch_bounds__(256)
void binB_kernel(const int* __restrict__ bcnt, const unsigned int* __restrict__ bdata,
                 int* __restrict__ offs, int* __restrict__ cntg,
                 int* __restrict__ col, int n){
  __shared__ int hist[NPB];
  __shared__ int sc[NPB];
  __shared__ int curp[NPB];
  int tid = threadIdx.x;
  int b = blockIdx.x;
  int base_node = b * NPB;

  if (tid < NPB) hist[tid] = 0;
  __syncthreads();
  #pragma unroll
  for (int g = 0; g < G; g++){
    int rc = bcnt[b * G + g]; if (rc > RCAP) rc = RCAP;
    size_t rb = (size_t)(b * G + g) * RCAP;
    for (int j = tid; j < rc; j += 256)
      atomicAdd(&hist[bdata[rb + j] >> 17], 1);
  }
  __syncthreads();
  if (tid < NPB) sc[tid] = hist[tid];
  __syncthreads();
  #pragma unroll
  for (int d1 = 1; d1 < NPB; d1 <<= 1){
    int v = 0;
    if (tid < NPB && tid >= d1) v = sc[tid - d1];
    __syncthreads();
    if (tid < NPB) sc[tid] += v;
    __syncthreads();
  }
  if (tid < NPB){
    int ex = tid ? sc[tid - 1] : 0;      // exclusive prefix
    int node = base_node + tid;
    if (node < n){
      offs[node] = b * BSTRIDE + ex;
      cntg[node] = hist[tid];
    }
    curp[tid] = ex;
  }
  __syncthreads();
  #pragma unroll
  for (int g = 0; g < G; g++){
    int rc = bcnt[b * G + g]; if (rc > RCAP) rc = RCAP;
    size_t rb = (size_t)(b * G + g) * RCAP;
    for (int j = tid; j < rc; j += 256){
      unsigned int u = bdata[rb + j];
      int r = atomicAdd(&curp[u >> 17], 1);
      col[b * BSTRIDE + r] = (int)(u & 0x1FFFFu);
    }
  }
}

// ---------------- GEMM1: [n,128]fp32 @ [128,128]fp32 -> bf16 ----------------
__global__ __launch_bounds__(256)
void gemm1_kernel(const float* __restrict__ X, const float* __restrict__ W,
                  unsigned short* __restrict__ Hb, int n){
  __shared__ float xs[16][132];   // transposed: xs[k][row]
  __shared__ float ws[16][128];
  int tid = threadIdx.x;
  int rg = tid >> 4, cg = tid & 15;
  int r0 = rg * 8, c0 = cg * 4;
  int row0 = blockIdx.x * 128;
  float acc[8][8];
  #pragma unroll
  for (int i = 0; i < 8; i++)
    #pragma unroll
    for (int j = 0; j < 8; j++) acc[i][j] = 0.f;

  for (int k0 = 0; k0 < 128; k0 += 16){
    #pragma unroll
    for (int l = 0; l < 2; l++){
      int f4 = tid + l * 256;
      int kk = f4 >> 5, cq = f4 & 31;
      float4 w = *(const float4*)(W + (size_t)(k0 + kk) * 128 + cq * 4);
      *(float4*)&ws[kk][cq * 4] = w;
    }
    #pragma unroll
    for (int l = 0; l < 2; l++){
      int f4 = tid + l * 256;
      int row = f4 >> 2, kq = f4 & 3;
      float4 v = make_float4(0.f, 0.f, 0.f, 0.f);
      if (row0 + row < n)
        v = *(const float4*)(X + (size_t)(row0 + row) * 128 + k0 + kq * 4);
      xs[kq*4+0][row] = v.x; xs[kq*4+1][row] = v.y;
      xs[kq*4+2][row] = v.z; xs[kq*4+3][row] = v.w;
    }
    __syncthreads();
    #pragma unroll
    for (int k = 0; k < 16; k++){
      float4 xa = *(const float4*)&xs[k][r0];
      float4 xb = *(const float4*)&xs[k][r0 + 4];
      float4 wa = *(const float4*)&ws[k][c0];
      float4 wb = *(const float4*)&ws[k][c0 + 64];
      float xr[8] = {xa.x,xa.y,xa.z,xa.w,xb.x,xb.y,xb.z,xb.w};
      float wr[8] = {wa.x,wa.y,wa.z,wa.w,wb.x,wb.y,wb.z,wb.w};
      #pragma unroll
      for (int i = 0; i < 8; i++)
        #pragma unroll
        for (int j = 0; j < 8; j++)
          acc[i][j] = fmaf(xr[i], wr[j], acc[i][j]);
    }
    __syncthreads();
  }
  #pragma unroll
  for (int i = 0; i < 8; i++){
    int r = row0 + r0 + i;
    if (r < n){
      ushort4 a4, b4;
      a4.x = f2bf(acc[i][0]); a4.y = f2bf(acc[i][1]);
      a4.z = f2bf(acc[i][2]); a4.w = f2bf(acc[i][3]);
      b4.x = f2bf(acc[i][4]); b4.y = f2bf(acc[i][5]);
      b4.z = f2bf(acc[i][6]); b4.w = f2bf(acc[i][7]);
      *(ushort4*)(Hb + (size_t)r * 128 + c0)      = a4;
      *(ushort4*)(Hb + (size_t)r * 128 + c0 + 64) = b4;
    }
  }
}

// ---------------- att1: bf16 input ----------------
__global__ __launch_bounds__(256)
void att1_kernel(const unsigned short* __restrict__ Hb, const float* __restrict__ As,
                 const float* __restrict__ Ad, float* __restrict__ asrc,
                 float* __restrict__ adst, int n){
  __shared__ float sa[128], sd[128];
  int tid = threadIdx.x;
  if (tid < 128){ sa[tid] = As[tid]; sd[tid] = Ad[tid]; }
  __syncthreads();
  int t = blockIdx.x * 256 + tid;
  if (t >= n * 8) return;
  int node = t >> 3, h = t & 7;
  const uint4* hp = (const uint4*)(Hb + (size_t)node * 128 + h * 16);
  uint4 u0 = hp[0], u1 = hp[1];
  unsigned int w[8] = {u0.x,u0.y,u0.z,u0.w,u1.x,u1.y,u1.z,u1.w};
  float s = 0.f, d = 0.f;
  #pragma unroll
  for (int q = 0; q < 8; q++){
    float2 p = bfpair(w[q]);
    s = fmaf(p.x, sa[h*16 + 2*q],     s);
    s = fmaf(p.y, sa[h*16 + 2*q + 1], s);
    d = fmaf(p.x, sd[h*16 + 2*q],     d);
    d = fmaf(p.y, sd[h*16 + 2*q + 1], d);
  }
  asrc[t] = s; adst[t] = d;
}

// ---------------- agg1: wave per node, 8 heads x 16 ch, bf16 gather --------
#define CAP1 64
__global__ __launch_bounds__(256)
void agg1_kernel(const unsigned short* __restrict__ Hb, const int* __restrict__ offs,
                 const int* __restrict__ cnt, const int* __restrict__ col,
                 const float* __restrict__ asrc, const float* __restrict__ adst,
                 const float* __restrict__ bias, float* __restrict__ G1, int n){
  __shared__ int   scol[4][CAP1];
  __shared__ float sex[4][CAP1][8];
  int lane = threadIdx.x & 63;
  int wid  = threadIdx.x >> 6;
  int node = blockIdx.x * 4 + wid;
  if (node >= n) return;
  int beg = offs[node], deg = cnt[node];

  int hA = lane & 7, iA = lane >> 3;
  int hB = lane >> 3;
  float adA = adst[node * 8 + hA];

  float2 acc = make_float2(0.f, 0.f);
  float m_run = -INFINITY;
  float denomA = 0.f;   // per-lane partial (head hA), rescaled per chunk

  for (int c0 = 0; c0 < deg; c0 += CAP1){
    int cdeg = min(CAP1, deg - c0);
    // phase A: logits in registers (static idx), chunk max per head
    float ev[8];
    float cm = -INFINITY;
    #pragma unroll
    for (int k = 0; k < 8; k++){
      int i = iA + k * 8;
      ev[k] = -INFINITY;
      if (i < cdeg){
        int s = col[beg + c0 + i];
        if (hA == 0) scol[wid][i] = s;
        float e = asrc[s * 8 + hA] + adA;
        e = e > 0.f ? e : 0.2f * e;
        ev[k] = e;
        cm = fmaxf(cm, e);
      }
    }
    cm = fmaxf(cm, __shfl_xor(cm, 8));
    cm = fmaxf(cm, __shfl_xor(cm, 16));
    cm = fmaxf(cm, __shfl_xor(cm, 32));
    float m_new = fmaxf(m_run, cm);
    float scaleA = __expf(m_run - m_new);   // first chunk: exp(-inf)=0
    denomA *= scaleA;
    #pragma unroll
    for (int k = 0; k < 8; k++){
      int i = iA + k * 8;
      if (i < cdeg){
        float ex = __expf(ev[k] - m_new);
        denomA += ex;
        sex[wid][i][hA] = ex;
      }
    }
    m_run = m_new;
    float scaleB = __shfl(scaleA, hB);
    acc.x *= scaleB; acc.y *= scaleB;
    lds_fence();
    // phase C: gather bf16 rows (4B/lane), unrolled x8 for MLP
    const unsigned int* Hu = (const unsigned int*)Hb;
    int i = 0;
    for (; i + 7 < cdeg; i += 8){
      int ss[8]; float xx[8]; unsigned int uu[8];
      #pragma unroll
      for (int k = 0; k < 8; k++){
        ss[k] = scol[wid][i + k];
        xx[k] = sex[wid][i + k][hB];
      }
      #pragma unroll
      for (int k = 0; k < 8; k++)
        uu[k] = Hu[(size_t)ss[k] * 64 + lane];
      #pragma unroll
      for (int k = 0; k < 8; k++){
        float2 f = bfpair(uu[k]);
        acc.x = fmaf(xx[k], f.x, acc.x);
        acc.y = fmaf(xx[k], f.y, acc.y);
      }
    }
    for (; i < cdeg; i++){
      int s = scol[wid][i];
      float x = sex[wid][i][hB];
      float2 f = bfpair(Hu[(size_t)s * 64 + lane]);
      acc.x = fmaf(x, f.x, acc.x);
      acc.y = fmaf(x, f.y, acc.y);
    }
  }
  denomA += __shfl_xor(denomA, 8);
  denomA += __shfl_xor(denomA, 16);
  denomA += __shfl_xor(denomA, 32);
  float denomB = __shfl(denomA, hB) + 1e-16f;
  float2 bv = ((const float2*)bias)[lane];
  float ox = acc.x / denomB + bv.x;
  float oy = acc.y / denomB + bv.y;
  ox = ox > 0.f ? ox : expm1f(ox);   // ELU
  oy = oy > 0.f ? oy : expm1f(oy);
  ((float2*)G1)[(size_t)node * 64 + lane] = make_float2(ox, oy);
}

// ---------------- GEMM2: [n,128]fp32 @ [128,40] -> bf16 ----------------
__global__ __launch_bounds__(256)
void gemm2_kernel(const float* __restrict__ X, const float* __restrict__ W,
                  unsigned short* __restrict__ Hb, int n){
  __shared__ float xs[16][132];
  __shared__ float ws[16][48];
  int tid = threadIdx.x;
  int rg = tid >> 3, cg = tid & 7;
  int r0 = rg * 4, c0 = cg * 6;
  int row0 = blockIdx.x * 128;
  float acc[4][6];
  #pragma unroll
  for (int i = 0; i < 4; i++)
    #pragma unroll
    for (int j = 0; j < 6; j++) acc[i][j] = 0.f;

  for (int k0 = 0; k0 < 128; k0 += 16){
    #pragma unroll
    for (int l = 0; l < 3; l++){
      int idx = tid + l * 256;
      int kk = idx / 48, c = idx % 48;
      ws[kk][c] = (c < 40) ? W[(size_t)(k0 + kk) * 40 + c] : 0.f;
    }
    #pragma unroll
    for (int l = 0; l < 2; l++){
      int f4 = tid + l * 256;
      int row = f4 >> 2, kq = f4 & 3;
      float4 v = make_float4(0.f, 0.f, 0.f, 0.f);
      if (row0 + row < n)
        v = *(const float4*)(X + (size_t)(row0 + row) * 128 + k0 + kq * 4);
      xs[kq*4+0][row] = v.x; xs[kq*4+1][row] = v.y;
      xs[kq*4+2][row] = v.z; xs[kq*4+3][row] = v.w;
    }
    __syncthreads();
    #pragma unroll
    for (int k = 0; k < 16; k++){
      float4 xa = *(const float4*)&xs[k][r0];
      float xr[4] = {xa.x, xa.y, xa.z, xa.w};
      float wr[6];
      #pragma unroll
      for (int j = 0; j < 6; j++) wr[j] = ws[k][c0 + j];
      #pragma unroll
      for (int i = 0; i < 4; i++)
        #pragma unroll
        for (int j = 0; j < 6; j++)
          acc[i][j] = fmaf(xr[i], wr[j], acc[i][j]);
    }
    __syncthreads();
  }
  #pragma unroll
  for (int i = 0; i < 4; i++){
    int r = row0 + r0 + i;
    if (r < n){
      #pragma unroll
      for (int j = 0; j < 6; j++){
        int c = c0 + j;
        if (c < 40) Hb[(size_t)r * 40 + c] = f2bf(acc[i][j]);
      }
    }
  }
}

// ---------------- att2: bf16 input ----------------
__global__ __launch_bounds__(256)
void att2_kernel(const unsigned short* __restrict__ Hb, const float* __restrict__ As,
                 const float* __restrict__ Ad, float* __restrict__ asrc,
                 float* __restrict__ adst, int n){
  int lane = threadIdx.x & 63;
  int node = blockIdx.x * 4 + (threadIdx.x >> 6);
  if (node >= n) return;
  float v = 0.f, a = 0.f, d = 0.f;
  if (lane < 40){
    v = bf2f(Hb[(size_t)node * 40 + lane]);
    a = As[lane];
    d = Ad[lane];
  }
  float s1 = wave_sum(v * a);
  float s2 = wave_sum(v * d);
  if (lane == 0){ asrc[node] = s1; adst[node] = s2; }
}

// ---------------- agg2 + bias + log_softmax, bf16 gather ----------------
#define CAP2 128
__global__ __launch_bounds__(256)
void agg2_kernel(const unsigned short* __restrict__ Hb, const int* __restrict__ offs,
                 const int* __restrict__ cnt, const int* __restrict__ col,
                 const float* __restrict__ asrc, const float* __restrict__ adst,
                 const float* __restrict__ bias, float* __restrict__ out, int n){
  __shared__ int   scol[4][CAP2];
  __shared__ float sex[4][CAP2];
  int lane = threadIdx.x & 63;
  int wid  = threadIdx.x >> 6;
  int node = blockIdx.x * 4 + wid;
  if (node >= n) return;
  int beg = offs[node], deg = cnt[node];
  float ad = adst[node];

  float acc = 0.f;
  float m_run = -INFINITY;
  float denom = 0.f;

  for (int c0 = 0; c0 < deg; c0 += CAP2){
    int cdeg = min(CAP2, deg - c0);
    float ev[2];
    float cm = -INFINITY;
    #pragma unroll
    for (int k = 0; k < 2; k++){
      int i = lane + k * 64;
      ev[k] = -INFINITY;
      if (i < cdeg){
        int s = col[beg + c0 + i];
        scol[wid][i] = s;
        float e = asrc[s] + ad;
        e = e > 0.f ? e : 0.2f * e;
        ev[k] = e;
        cm = fmaxf(cm, e);
      }
    }
    cm = wave_max(cm);
    float m_new = fmaxf(m_run, cm);
    float scale = __expf(m_run - m_new);
    float part = 0.f;
    #pragma unroll
    for (int k = 0; k < 2; k++){
      int i = lane + k * 64;
      if (i < cdeg){
        float ex = __expf(ev[k] - m_new);
        part += ex;
        sex[wid][i] = ex;
      }
    }
    denom = denom * scale + wave_sum(part);
    acc *= scale;
    m_run = m_new;
    lds_fence();
    int i = 0;
    for (; i + 7 < cdeg; i += 8){
      int ss[8]; float xx[8]; float ff[8];
      #pragma unroll
      for (int k = 0; k < 8; k++){
        ss[k] = scol[wid][i + k];
        xx[k] = sex[wid][i + k];
      }
      #pragma unroll
      for (int k = 0; k < 8; k++)
        ff[k] = (lane < 40) ? bf2f(Hb[(size_t)ss[k] * 40 + lane]) : 0.f;
      #pragma unroll
      for (int k = 0; k < 8; k++)
        acc = fmaf(xx[k], ff[k], acc);
    }
    for (; i < cdeg; i++){
      int s = scol[wid][i];
      float x = sex[wid][i];
      float f = (lane < 40) ? bf2f(Hb[(size_t)s * 40 + lane]) : 0.f;
      acc = fmaf(x, f, acc);
    }
  }
  float val = 0.f;
  if (lane < 40) val = acc / (denom + 1e-16f) + bias[lane];

  float mx = wave_max(lane < 40 ? val : -INFINITY);
  float ssum = wave_sum(lane < 40 ? __expf(val - mx) : 0.f);
  float ls = logf(ssum);
  if (lane < 40) out[(size_t)node * 40 + lane] = val - mx - ls;
}

// ---------------- launch ----------------
extern "C" void kernel_launch(void* const* d_in, const int* in_sizes, int n_in,
                              void* d_out, int out_size, void* d_ws, size_t ws_size,
                              hipStream_t stream){
  const float* x   = (const float*)d_in[0];
  const int*   ei  = (const int*)d_in[1];
  const float* W1  = (const float*)d_in[2];
  const float* as1 = (const float*)d_in[3];
  const float* ad1 = (const float*)d_in[4];
  const float* b1  = (const float*)d_in[5];
  const float* W2  = (const float*)d_in[6];
  const float* as2 = (const float*)d_in[7];
  const float* ad2 = (const float*)d_in[8];
  const float* b2  = (const float*)d_in[9];
  float* out = (float*)d_out;

  int n = in_sizes[0] / 128;
  int E = in_sizes[1] / 2;
  const int* src = ei;
  const int* dst = ei + E;
  int tot = E + n;
  int nb = (n + NPB - 1) / NPB;       // buckets
  int nr = nb * G;                    // counter replicas

  char* w = (char*)d_ws;
  size_t off = 0;
  auto alloc = [&](size_t bytes){
    size_t r = off; off += (bytes + 255) & ~(size_t)255; return r;
  };
  int* bcnt = (int*)(w + alloc((size_t)nr * 4));
  unsigned int* bdata = (unsigned int*)(w + alloc((size_t)nr * RCAP * 4));
  int* offs = (int*)(w + alloc((size_t)n * 4));
  int* cnt  = (int*)(w + alloc((size_t)n * 4));
  int* col  = (int*)(w + alloc((size_t)nb * BSTRIDE * 4));
  unsigned short* h1b = (unsigned short*)(w + alloc((size_t)n * 128 * 2));
  float* g1   = (float*)(w + alloc((size_t)n * 128 * 4));
  float* s1   = (float*)(w + alloc((size_t)n * 8 * 4));
  float* t1   = (float*)(w + alloc((size_t)n * 8 * 4));
  unsigned short* h2b = h1b;   // layer-2 aliases (h1b dead after agg1)
  float* s2 = s1;
  float* t2 = t1;
  (void)ws_size; (void)n_in; (void)out_size;

  zero_bcnt_kernel<<<(nr + 255) / 256, 256, 0, stream>>>(bcnt, nr);
  binA_kernel<<<(tot + 255) / 256, 256, 0, stream>>>(src, dst, bcnt, bdata, E, tot);
  binB_kernel<<<nb, 256, 0, stream>>>(bcnt, bdata, offs, cnt, col, n);

  gemm1_kernel<<<(n + 127) / 128, 256, 0, stream>>>(x, W1, h1b, n);
  att1_kernel<<<(n * 8 + 255) / 256, 256, 0, stream>>>(h1b, as1, ad1, s1, t1, n);
  agg1_kernel<<<(n + 3) / 4, 256, 0, stream>>>(h1b, offs, cnt, col, s1, t1, b1, g1, n);

  gemm2_kernel<<<(n + 127) / 128, 256, 0, stream>>>(g1, W2, h2b, n);
  att2_kernel<<<(n + 3) / 4, 256, 0, stream>>>(h2b, as2, ad2, s2, t2, n);
  agg2_kernel<<<(n + 3) / 4, 256, 0, stream>>>(h2b, offs, cnt, col, s2, t2, b2, out, n);
}

// Round 7
// 502.719 us; speedup vs baseline: 1.7411x; 1.0867x over previous
//
#include <hip/hip_runtime.h>
#include <math.h>

// GAT 2-layer: N=100K nodes, E=1.6M edges + self loops.
// CSR build: bucketed binning with XCD-privatized counters (round-6: fixed
// binA atomic serialization; 437us -> off top-5).
// Round-7 change: scalarized aggregation phase C.
//   Round-6 counters: agg2 118us, FETCH 104MB (mem floor ~17us), VALU 38%
//   -> per-edge overhead bound (LDS scol/sex round trips + 64-bit addr calc).
//   Fix: keep col/ex in registers; broadcast src via v_readlane (uniform ->
//   SALU row pointer + saddr loads), ex via readlane/shfl. No LDS in aggs.
// Feature arrays gathered per-edge stored bf16 (round-4), fp32 accumulate.

#define NPB   32           // nodes per bucket (dst>>5)
#define G     8            // counter replicas (~per-XCD via blockIdx&7)
#define RCAP  192          // capacity per (bucket,replica)
#define BSTRIDE (G*RCAP)   // col entries per bucket

__device__ __forceinline__ float wave_max(float v){
  #pragma unroll
  for (int m = 1; m < 64; m <<= 1) v = fmaxf(v, __shfl_xor(v, m));
  return v;
}
__device__ __forceinline__ float wave_sum(float v){
  #pragma unroll
  for (int m = 1; m < 64; m <<= 1) v += __shfl_xor(v, m);
  return v;
}
// wave-uniform broadcasts (compiler knows readlane result is uniform -> SALU)
__device__ __forceinline__ int lane_bcast_i(int v, int l){
  return __builtin_amdgcn_readlane(v, l);
}
__device__ __forceinline__ float lane_bcast_f(float v, int l){
  return __uint_as_float((unsigned)__builtin_amdgcn_readlane(__float_as_int(v), l));
}

// bf16 helpers (RNE pack, shift unpack)
__device__ __forceinline__ unsigned short f2bf(float f){
  unsigned int u = __float_as_uint(f);
  u += 0x7FFFu + ((u >> 16) & 1u);
  return (unsigned short)(u >> 16);
}
__device__ __forceinline__ float bf2f(unsigned short b){
  return __uint_as_float(((unsigned int)b) << 16);
}
__device__ __forceinline__ float2 bfpair(unsigned int u){
  float2 r;
  r.x = __uint_as_float(u << 16);
  r.y = __uint_as_float(u & 0xFFFF0000u);
  return r;
}

// ---------------- CSR build: bucketed binning ----------------

__global__ void zero_bcnt_kernel(int* __restrict__ p, int nr){
  int i = blockIdx.x * 256 + threadIdx.x;
  if (i < nr) p[i] = 0;
}

__global__ void binA_kernel(const int* __restrict__ src, const int* __restrict__ dst,
                            int* __restrict__ bcnt, unsigned int* __restrict__ bdata,
                            int E, int tot){
  int i = blockIdx.x * 256 + threadIdx.x;
  if (i >= tot) return;
  int s, d;
  if (i < E){ s = src[i]; d = dst[i]; } else { s = i - E; d = s; }
  int b = d >> 5;
  int r = b * G + (blockIdx.x & (G - 1));
  int pos = atomicAdd(&bcnt[r], 1);
  if (pos < RCAP)
    bdata[(size_t)r * RCAP + pos] = (unsigned int)s | ((unsigned int)(d & 31) << 17);
}

__global__ __launch_bounds__(256)
void binB_kernel(const int* __restrict__ bcnt, const unsigned int* __restrict__ bdata,
                 int* __restrict__ offs, int* __restrict__ cntg,
                 int* __restrict__ col, int n){
  __shared__ int hist[NPB];
  __shared__ int sc[NPB];
  __shared__ int curp[NPB];
  int tid = threadIdx.x;
  int b = blockIdx.x;
  int base_node = b * NPB;

  if (tid < NPB) hist[tid] = 0;
  __syncthreads();
  #pragma unroll
  for (int g = 0; g < G; g++){
    int rc = bcnt[b * G + g]; if (rc > RCAP) rc = RCAP;
    size_t rb = (size_t)(b * G + g) * RCAP;
    for (int j = tid; j < rc; j += 256)
      atomicAdd(&hist[bdata[rb + j] >> 17], 1);
  }
  __syncthreads();
  if (tid < NPB) sc[tid] = hist[tid];
  __syncthreads();
  #pragma unroll
  for (int d1 = 1; d1 < NPB; d1 <<= 1){
    int v = 0;
    if (tid < NPB && tid >= d1) v = sc[tid - d1];
    __syncthreads();
    if (tid < NPB) sc[tid] += v;
    __syncthreads();
  }
  if (tid < NPB){
    int ex = tid ? sc[tid - 1] : 0;
    int node = base_node + tid;
    if (node < n){
      offs[node] = b * BSTRIDE + ex;
      cntg[node] = hist[tid];
    }
    curp[tid] = ex;
  }
  __syncthreads();
  #pragma unroll
  for (int g = 0; g < G; g++){
    int rc = bcnt[b * G + g]; if (rc > RCAP) rc = RCAP;
    size_t rb = (size_t)(b * G + g) * RCAP;
    for (int j = tid; j < rc; j += 256){
      unsigned int u = bdata[rb + j];
      int r = atomicAdd(&curp[u >> 17], 1);
      col[b * BSTRIDE + r] = (int)(u & 0x1FFFFu);
    }
  }
}

// ---------------- GEMM1: [n,128]fp32 @ [128,128]fp32 -> bf16 ----------------
__global__ __launch_bounds__(256)
void gemm1_kernel(const float* __restrict__ X, const float* __restrict__ W,
                  unsigned short* __restrict__ Hb, int n){
  __shared__ float xs[16][132];
  __shared__ float ws[16][128];
  int tid = threadIdx.x;
  int rg = tid >> 4, cg = tid & 15;
  int r0 = rg * 8, c0 = cg * 4;
  int row0 = blockIdx.x * 128;
  float acc[8][8];
  #pragma unroll
  for (int i = 0; i < 8; i++)
    #pragma unroll
    for (int j = 0; j < 8; j++) acc[i][j] = 0.f;

  for (int k0 = 0; k0 < 128; k0 += 16){
    #pragma unroll
    for (int l = 0; l < 2; l++){
      int f4 = tid + l * 256;
      int kk = f4 >> 5, cq = f4 & 31;
      float4 w = *(const float4*)(W + (size_t)(k0 + kk) * 128 + cq * 4);
      *(float4*)&ws[kk][cq * 4] = w;
    }
    #pragma unroll
    for (int l = 0; l < 2; l++){
      int f4 = tid + l * 256;
      int row = f4 >> 2, kq = f4 & 3;
      float4 v = make_float4(0.f, 0.f, 0.f, 0.f);
      if (row0 + row < n)
        v = *(const float4*)(X + (size_t)(row0 + row) * 128 + k0 + kq * 4);
      xs[kq*4+0][row] = v.x; xs[kq*4+1][row] = v.y;
      xs[kq*4+2][row] = v.z; xs[kq*4+3][row] = v.w;
    }
    __syncthreads();
    #pragma unroll
    for (int k = 0; k < 16; k++){
      float4 xa = *(const float4*)&xs[k][r0];
      float4 xb = *(const float4*)&xs[k][r0 + 4];
      float4 wa = *(const float4*)&ws[k][c0];
      float4 wb = *(const float4*)&ws[k][c0 + 64];
      float xr[8] = {xa.x,xa.y,xa.z,xa.w,xb.x,xb.y,xb.z,xb.w};
      float wr[8] = {wa.x,wa.y,wa.z,wa.w,wb.x,wb.y,wb.z,wb.w};
      #pragma unroll
      for (int i = 0; i < 8; i++)
        #pragma unroll
        for (int j = 0; j < 8; j++)
          acc[i][j] = fmaf(xr[i], wr[j], acc[i][j]);
    }
    __syncthreads();
  }
  #pragma unroll
  for (int i = 0; i < 8; i++){
    int r = row0 + r0 + i;
    if (r < n){
      ushort4 a4, b4;
      a4.x = f2bf(acc[i][0]); a4.y = f2bf(acc[i][1]);
      a4.z = f2bf(acc[i][2]); a4.w = f2bf(acc[i][3]);
      b4.x = f2bf(acc[i][4]); b4.y = f2bf(acc[i][5]);
      b4.z = f2bf(acc[i][6]); b4.w = f2bf(acc[i][7]);
      *(ushort4*)(Hb + (size_t)r * 128 + c0)      = a4;
      *(ushort4*)(Hb + (size_t)r * 128 + c0 + 64) = b4;
    }
  }
}

// ---------------- att1: bf16 input ----------------
__global__ __launch_bounds__(256)
void att1_kernel(const unsigned short* __restrict__ Hb, const float* __restrict__ As,
                 const float* __restrict__ Ad, float* __restrict__ asrc,
                 float* __restrict__ adst, int n){
  __shared__ float sa[128], sd[128];
  int tid = threadIdx.x;
  if (tid < 128){ sa[tid] = As[tid]; sd[tid] = Ad[tid]; }
  __syncthreads();
  int t = blockIdx.x * 256 + tid;
  if (t >= n * 8) return;
  int node = t >> 3, h = t & 7;
  const uint4* hp = (const uint4*)(Hb + (size_t)node * 128 + h * 16);
  uint4 u0 = hp[0], u1 = hp[1];
  unsigned int w[8] = {u0.x,u0.y,u0.z,u0.w,u1.x,u1.y,u1.z,u1.w};
  float s = 0.f, d = 0.f;
  #pragma unroll
  for (int q = 0; q < 8; q++){
    float2 p = bfpair(w[q]);
    s = fmaf(p.x, sa[h*16 + 2*q],     s);
    s = fmaf(p.y, sa[h*16 + 2*q + 1], s);
    d = fmaf(p.x, sd[h*16 + 2*q],     d);
    d = fmaf(p.y, sd[h*16 + 2*q + 1], d);
  }
  asrc[t] = s; adst[t] = d;
}

// ---------------- agg1: wave per node, scalarized phase C ----------------
// Phase A: lane=(slot iA=lane>>3, head hA=lane&7); edge i=iA+k*8 in regs.
// Phase C: lane owns channel pair (2 bf16 = uint), head hB=lane>>3.
//   Edge (j+k*8): src via readlane(sv[k], j*8) -> SALU row base;
//   ex via shfl(xv[k], j*8+hB). Inactive slots: sv=0, xv=0 (row-0 load, 0 fma).
__global__ __launch_bounds__(256)
void agg1_kernel(const unsigned short* __restrict__ Hb, const int* __restrict__ offs,
                 const int* __restrict__ cnt, const int* __restrict__ col,
                 const float* __restrict__ asrc, const float* __restrict__ adst,
                 const float* __restrict__ bias, float* __restrict__ G1, int n){
  int lane = threadIdx.x & 63;
  int wid  = threadIdx.x >> 6;
  int node = blockIdx.x * 4 + wid;
  if (node >= n) return;
  int beg = offs[node], deg = cnt[node];

  int hA = lane & 7, iA = lane >> 3;
  int hB = lane >> 3;
  float adA = adst[(unsigned)node * 8u + hA];
  const unsigned int* Hu = (const unsigned int*)Hb;

  float2 acc = make_float2(0.f, 0.f);
  float m_run = -INFINITY;
  float denomA = 0.f;   // per-lane partial (head hA)

  for (int c0 = 0; c0 < deg; c0 += 64){
    int cdeg = min(64, deg - c0);
    int sv[8]; float xv[8];
    float cm = -INFINITY;
    #pragma unroll
    for (int k = 0; k < 8; k++){
      int i = iA + k * 8;
      sv[k] = 0; xv[k] = -INFINITY;
      if (i < cdeg){
        int s = col[beg + c0 + i];
        sv[k] = s;
        float e = asrc[(unsigned)s * 8u + hA] + adA;
        e = e > 0.f ? e : 0.2f * e;
        xv[k] = e;
        cm = fmaxf(cm, e);
      }
    }
    cm = fmaxf(cm, __shfl_xor(cm, 8));
    cm = fmaxf(cm, __shfl_xor(cm, 16));
    cm = fmaxf(cm, __shfl_xor(cm, 32));
    float m_new = fmaxf(m_run, cm);
    float scaleA = __expf(m_run - m_new);   // first chunk: exp(-inf)=0
    denomA *= scaleA;
    #pragma unroll
    for (int k = 0; k < 8; k++){
      int i = iA + k * 8;
      if (i < cdeg){
        float ex = __expf(xv[k] - m_new);
        xv[k] = ex;
        denomA += ex;
      } else xv[k] = 0.f;
    }
    m_run = m_new;
    float scaleB = __shfl(scaleA, hB);
    acc.x *= scaleB; acc.y *= scaleB;
    // phase C: 8-edge groups, static unroll, zero-weight padding
    #pragma unroll
    for (int k = 0; k < 8; k++){
      if (k * 8 >= cdeg) break;
      #pragma unroll
      for (int j = 0; j < 8; j++){
        int sk = lane_bcast_i(sv[k], j * 8);
        float exk = __shfl(xv[k], j * 8 + hB);
        float2 f = bfpair(Hu[(unsigned)sk * 64u + lane]);
        acc.x = fmaf(exk, f.x, acc.x);
        acc.y = fmaf(exk, f.y, acc.y);
      }
    }
  }
  denomA += __shfl_xor(denomA, 8);
  denomA += __shfl_xor(denomA, 16);
  denomA += __shfl_xor(denomA, 32);
  float denomB = __shfl(denomA, hB) + 1e-16f;
  float2 bv = ((const float2*)bias)[lane];
  float ox = acc.x / denomB + bv.x;
  float oy = acc.y / denomB + bv.y;
  ox = ox > 0.f ? ox : expm1f(ox);   // ELU
  oy = oy > 0.f ? oy : expm1f(oy);
  ((float2*)G1)[(size_t)node * 64 + lane] = make_float2(ox, oy);
}

// ---------------- GEMM2: [n,128]fp32 @ [128,40] -> bf16 ----------------
__global__ __launch_bounds__(256)
void gemm2_kernel(const float* __restrict__ X, const float* __restrict__ W,
                  unsigned short* __restrict__ Hb, int n){
  __shared__ float xs[16][132];
  __shared__ float ws[16][48];
  int tid = threadIdx.x;
  int rg = tid >> 3, cg = tid & 7;
  int r0 = rg * 4, c0 = cg * 6;
  int row0 = blockIdx.x * 128;
  float acc[4][6];
  #pragma unroll
  for (int i = 0; i < 4; i++)
    #pragma unroll
    for (int j = 0; j < 6; j++) acc[i][j] = 0.f;

  for (int k0 = 0; k0 < 128; k0 += 16){
    #pragma unroll
    for (int l = 0; l < 3; l++){
      int idx = tid + l * 256;
      int kk = idx / 48, c = idx % 48;
      ws[kk][c] = (c < 40) ? W[(size_t)(k0 + kk) * 40 + c] : 0.f;
    }
    #pragma unroll
    for (int l = 0; l < 2; l++){
      int f4 = tid + l * 256;
      int row = f4 >> 2, kq = f4 & 3;
      float4 v = make_float4(0.f, 0.f, 0.f, 0.f);
      if (row0 + row < n)
        v = *(const float4*)(X + (size_t)(row0 + row) * 128 + k0 + kq * 4);
      xs[kq*4+0][row] = v.x; xs[kq*4+1][row] = v.y;
      xs[kq*4+2][row] = v.z; xs[kq*4+3][row] = v.w;
    }
    __syncthreads();
    #pragma unroll
    for (int k = 0; k < 16; k++){
      float4 xa = *(const float4*)&xs[k][r0];
      float xr[4] = {xa.x, xa.y, xa.z, xa.w};
      float wr[6];
      #pragma unroll
      for (int j = 0; j < 6; j++) wr[j] = ws[k][c0 + j];
      #pragma unroll
      for (int i = 0; i < 4; i++)
        #pragma unroll
        for (int j = 0; j < 6; j++)
          acc[i][j] = fmaf(xr[i], wr[j], acc[i][j]);
    }
    __syncthreads();
  }
  #pragma unroll
  for (int i = 0; i < 4; i++){
    int r = row0 + r0 + i;
    if (r < n){
      #pragma unroll
      for (int j = 0; j < 6; j++){
        int c = c0 + j;
        if (c < 40) Hb[(size_t)r * 40 + c] = f2bf(acc[i][j]);
      }
    }
  }
}

// ---------------- att2: bf16 input ----------------
__global__ __launch_bounds__(256)
void att2_kernel(const unsigned short* __restrict__ Hb, const float* __restrict__ As,
                 const float* __restrict__ Ad, float* __restrict__ asrc,
                 float* __restrict__ adst, int n){
  int lane = threadIdx.x & 63;
  int node = blockIdx.x * 4 + (threadIdx.x >> 6);
  if (node >= n) return;
  float v = 0.f, a = 0.f, d = 0.f;
  if (lane < 40){
    v = bf2f(Hb[(size_t)node * 40 + lane]);
    a = As[lane];
    d = Ad[lane];
  }
  float s1 = wave_sum(v * a);
  float s2 = wave_sum(v * d);
  if (lane == 0){ asrc[node] = s1; adst[node] = s2; }
}

// ---------------- agg2 + bias + log_softmax, scalarized ----------------
// Phase A: lane=edge in 64-chunk (s, ex in regs).
// Phase C: lanes 0..39 = channels; src via readlane -> SALU row base.
__global__ __launch_bounds__(256)
void agg2_kernel(const unsigned short* __restrict__ Hb, const int* __restrict__ offs,
                 const int* __restrict__ cnt, const int* __restrict__ col,
                 const float* __restrict__ asrc, const float* __restrict__ adst,
                 const float* __restrict__ bias, float* __restrict__ out, int n){
  int lane = threadIdx.x & 63;
  int wid  = threadIdx.x >> 6;
  int node = blockIdx.x * 4 + wid;
  if (node >= n) return;
  int beg = offs[node], deg = cnt[node];
  float ad = adst[node];
  unsigned choff = (lane < 40) ? (unsigned)lane : 0u;  // clamped channel

  float acc = 0.f;
  float m_run = -INFINITY;
  float denom = 0.f;

  for (int c0 = 0; c0 < deg; c0 += 64){
    int cdeg = min(64, deg - c0);
    int s = 0; float ev = -INFINITY;
    if (lane < cdeg){
      s = col[beg + c0 + lane];
      float e = asrc[s] + ad;
      ev = e > 0.f ? e : 0.2f * e;
    }
    float cm = wave_max(ev);
    float m_new = fmaxf(m_run, cm);
    float scale = __expf(m_run - m_new);
    float ex = (lane < cdeg) ? __expf(ev - m_new) : 0.f;
    denom = denom * scale + wave_sum(ex);
    acc *= scale;
    m_run = m_new;
    // phase C: 8-edge groups, static unroll, zero-weight padding
    #pragma unroll
    for (int kb = 0; kb < 8; kb++){
      if (kb * 8 >= cdeg) break;
      #pragma unroll
      for (int j = 0; j < 8; j++){
        int k = kb * 8 + j;
        int sk = lane_bcast_i(s, k);
        float exk = lane_bcast_f(ex, k);
        float f = bf2f(Hb[(unsigned)sk * 40u + choff]);
        acc = fmaf(exk, f, acc);
      }
    }
  }
  float val = 0.f;
  if (lane < 40) val = acc / (denom + 1e-16f) + bias[lane];

  float mx = wave_max(lane < 40 ? val : -INFINITY);
  float ssum = wave_sum(lane < 40 ? __expf(val - mx) : 0.f);
  float ls = logf(ssum);
  if (lane < 40) out[(size_t)node * 40 + lane] = val - mx - ls;
}

// ---------------- launch ----------------
extern "C" void kernel_launch(void* const* d_in, const int* in_sizes, int n_in,
                              void* d_out, int out_size, void* d_ws, size_t ws_size,
                              hipStream_t stream){
  const float* x   = (const float*)d_in[0];
  const int*   ei  = (const int*)d_in[1];
  const float* W1  = (const float*)d_in[2];
  const float* as1 = (const float*)d_in[3];
  const float* ad1 = (const float*)d_in[4];
  const float* b1  = (const float*)d_in[5];
  const float* W2  = (const float*)d_in[6];
  const float* as2 = (const float*)d_in[7];
  const float* ad2 = (const float*)d_in[8];
  const float* b2  = (const float*)d_in[9];
  float* out = (float*)d_out;

  int n = in_sizes[0] / 128;
  int E = in_sizes[1] / 2;
  const int* src = ei;
  const int* dst = ei + E;
  int tot = E + n;
  int nb = (n + NPB - 1) / NPB;       // buckets
  int nr = nb * G;                    // counter replicas

  char* w = (char*)d_ws;
  size_t off = 0;
  auto alloc = [&](size_t bytes){
    size_t r = off; off += (bytes + 255) & ~(size_t)255; return r;
  };
  int* bcnt = (int*)(w + alloc((size_t)nr * 4));
  unsigned int* bdata = (unsigned int*)(w + alloc((size_t)nr * RCAP * 4));
  int* offs = (int*)(w + alloc((size_t)n * 4));
  int* cnt  = (int*)(w + alloc((size_t)n * 4));
  int* col  = (int*)(w + alloc((size_t)nb * BSTRIDE * 4));
  unsigned short* h1b = (unsigned short*)(w + alloc((size_t)n * 128 * 2));
  float* g1   = (float*)(w + alloc((size_t)n * 128 * 4));
  float* s1   = (float*)(w + alloc((size_t)n * 8 * 4));
  float* t1   = (float*)(w + alloc((size_t)n * 8 * 4));
  unsigned short* h2b = h1b;   // layer-2 aliases (h1b dead after agg1)
  float* s2 = s1;
  float* t2 = t1;
  (void)ws_size; (void)n_in; (void)out_size;

  zero_bcnt_kernel<<<(nr + 255) / 256, 256, 0, stream>>>(bcnt, nr);
  binA_kernel<<<(tot + 255) / 256, 256, 0, stream>>>(src, dst, bcnt, bdata, E, tot);
  binB_kernel<<<nb, 256, 0, stream>>>(bcnt, bdata, offs, cnt, col, n);

  gemm1_kernel<<<(n + 127) / 128, 256, 0, stream>>>(x, W1, h1b, n);
  att1_kernel<<<(n * 8 + 255) / 256, 256, 0, stream>>>(h1b, as1, ad1, s1, t1, n);
  agg1_kernel<<<(n + 3) / 4, 256, 0, stream>>>(h1b, offs, cnt, col, s1, t1, b1, g1, n);

  gemm2_kernel<<<(n + 127) / 128, 256, 0, stream>>>(g1, W2, h2b, n);
  att2_kernel<<<(n + 3) / 4, 256, 0, stream>>>(h2b, as2, ad2, s2, t2, n);
  agg2_kernel<<<(n + 3) / 4, 256, 0, stream>>>(h2b, offs, cnt, col, s2, t2, b2, out, n);
}

// Round 9
// 475.627 us; speedup vs baseline: 1.8403x; 1.0570x over previous
//
#include <hip/hip_runtime.h>
#include <math.h>

// GAT 2-layer: N=100K nodes, E=1.6M edges + self loops.
// CSR build: bucketed binning, XCD-privatized counters (round 6).
// Aggregation: wave per node, flash-style online softmax, register-scalarized
// phase C (round 7), bf16 feature gathers (round 4), fp32 accumulate.
// Round-8 change: explicit 4-phase staging per 8-edge group in phase C
//   (batch broadcasts -> batch loads -> math). Round-7 counters showed agg1
//   124us, 2.6TB/s, VALU 53%, occ 47% -> latency-bound, ~1 load in flight
//   (loads were emitted adjacent to dependent fma). Also __expf-based ELU.
// NOTE: round-8 submission hit GPUAcquisitionTimeout (infra); identical
// resubmission to measure the staged-loads theory.

#define NPB   32           // nodes per bucket (dst>>5)
#define G     8            // counter replicas (~per-XCD via blockIdx&7)
#define RCAP  192          // capacity per (bucket,replica)
#define BSTRIDE (G*RCAP)   // col entries per bucket

__device__ __forceinline__ float wave_max(float v){
  #pragma unroll
  for (int m = 1; m < 64; m <<= 1) v = fmaxf(v, __shfl_xor(v, m));
  return v;
}
__device__ __forceinline__ float wave_sum(float v){
  #pragma unroll
  for (int m = 1; m < 64; m <<= 1) v += __shfl_xor(v, m);
  return v;
}
__device__ __forceinline__ int lane_bcast_i(int v, int l){
  return __builtin_amdgcn_readlane(v, l);
}
__device__ __forceinline__ float lane_bcast_f(float v, int l){
  return __uint_as_float((unsigned)__builtin_amdgcn_readlane(__float_as_int(v), l));
}

// bf16 helpers (RNE pack, shift unpack)
__device__ __forceinline__ unsigned short f2bf(float f){
  unsigned int u = __float_as_uint(f);
  u += 0x7FFFu + ((u >> 16) & 1u);
  return (unsigned short)(u >> 16);
}
__device__ __forceinline__ float bf2f(unsigned short b){
  return __uint_as_float(((unsigned int)b) << 16);
}
__device__ __forceinline__ float2 bfpair(unsigned int u){
  float2 r;
  r.x = __uint_as_float(u << 16);
  r.y = __uint_as_float(u & 0xFFFF0000u);
  return r;
}

// ---------------- CSR build: bucketed binning ----------------

__global__ void zero_bcnt_kernel(int* __restrict__ p, int nr){
  int i = blockIdx.x * 256 + threadIdx.x;
  if (i < nr) p[i] = 0;
}

__global__ void binA_kernel(const int* __restrict__ src, const int* __restrict__ dst,
                            int* __restrict__ bcnt, unsigned int* __restrict__ bdata,
                            int E, int tot){
  int i = blockIdx.x * 256 + threadIdx.x;
  if (i >= tot) return;
  int s, d;
  if (i < E){ s = src[i]; d = dst[i]; } else { s = i - E; d = s; }
  int b = d >> 5;
  int r = b * G + (blockIdx.x & (G - 1));
  int pos = atomicAdd(&bcnt[r], 1);
  if (pos < RCAP)
    bdata[(size_t)r * RCAP + pos] = (unsigned int)s | ((unsigned int)(d & 31) << 17);
}

__global__ __launch_bounds__(256)
void binB_kernel(const int* __restrict__ bcnt, const unsigned int* __restrict__ bdata,
                 int* __restrict__ offs, int* __restrict__ cntg,
                 int* __restrict__ col, int n){
  __shared__ int hist[NPB];
  __shared__ int sc[NPB];
  __shared__ int curp[NPB];
  int tid = threadIdx.x;
  int b = blockIdx.x;
  int base_node = b * NPB;

  if (tid < NPB) hist[tid] = 0;
  __syncthreads();
  #pragma unroll
  for (int g = 0; g < G; g++){
    int rc = bcnt[b * G + g]; if (rc > RCAP) rc = RCAP;
    size_t rb = (size_t)(b * G + g) * RCAP;
    for (int j = tid; j < rc; j += 256)
      atomicAdd(&hist[bdata[rb + j] >> 17], 1);
  }
  __syncthreads();
  if (tid < NPB) sc[tid] = hist[tid];
  __syncthreads();
  #pragma unroll
  for (int d1 = 1; d1 < NPB; d1 <<= 1){
    int v = 0;
    if (tid < NPB && tid >= d1) v = sc[tid - d1];
    __syncthreads();
    if (tid < NPB) sc[tid] += v;
    __syncthreads();
  }
  if (tid < NPB){
    int ex = tid ? sc[tid - 1] : 0;
    int node = base_node + tid;
    if (node < n){
      offs[node] = b * BSTRIDE + ex;
      cntg[node] = hist[tid];
    }
    curp[tid] = ex;
  }
  __syncthreads();
  #pragma unroll
  for (int g = 0; g < G; g++){
    int rc = bcnt[b * G + g]; if (rc > RCAP) rc = RCAP;
    size_t rb = (size_t)(b * G + g) * RCAP;
    for (int j = tid; j < rc; j += 256){
      unsigned int u = bdata[rb + j];
      int r = atomicAdd(&curp[u >> 17], 1);
      col[b * BSTRIDE + r] = (int)(u & 0x1FFFFu);
    }
  }
}

// ---------------- GEMM1: [n,128]fp32 @ [128,128]fp32 -> bf16 ----------------
__global__ __launch_bounds__(256)
void gemm1_kernel(const float* __restrict__ X, const float* __restrict__ W,
                  unsigned short* __restrict__ Hb, int n){
  __shared__ float xs[16][132];
  __shared__ float ws[16][128];
  int tid = threadIdx.x;
  int rg = tid >> 4, cg = tid & 15;
  int r0 = rg * 8, c0 = cg * 4;
  int row0 = blockIdx.x * 128;
  float acc[8][8];
  #pragma unroll
  for (int i = 0; i < 8; i++)
    #pragma unroll
    for (int j = 0; j < 8; j++) acc[i][j] = 0.f;

  for (int k0 = 0; k0 < 128; k0 += 16){
    #pragma unroll
    for (int l = 0; l < 2; l++){
      int f4 = tid + l * 256;
      int kk = f4 >> 5, cq = f4 & 31;
      float4 w = *(const float4*)(W + (size_t)(k0 + kk) * 128 + cq * 4);
      *(float4*)&ws[kk][cq * 4] = w;
    }
    #pragma unroll
    for (int l = 0; l < 2; l++){
      int f4 = tid + l * 256;
      int row = f4 >> 2, kq = f4 & 3;
      float4 v = make_float4(0.f, 0.f, 0.f, 0.f);
      if (row0 + row < n)
        v = *(const float4*)(X + (size_t)(row0 + row) * 128 + k0 + kq * 4);
      xs[kq*4+0][row] = v.x; xs[kq*4+1][row] = v.y;
      xs[kq*4+2][row] = v.z; xs[kq*4+3][row] = v.w;
    }
    __syncthreads();
    #pragma unroll
    for (int k = 0; k < 16; k++){
      float4 xa = *(const float4*)&xs[k][r0];
      float4 xb = *(const float4*)&xs[k][r0 + 4];
      float4 wa = *(const float4*)&ws[k][c0];
      float4 wb = *(const float4*)&ws[k][c0 + 64];
      float xr[8] = {xa.x,xa.y,xa.z,xa.w,xb.x,xb.y,xb.z,xb.w};
      float wr[8] = {wa.x,wa.y,wa.z,wa.w,wb.x,wb.y,wb.z,wb.w};
      #pragma unroll
      for (int i = 0; i < 8; i++)
        #pragma unroll
        for (int j = 0; j < 8; j++)
          acc[i][j] = fmaf(xr[i], wr[j], acc[i][j]);
    }
    __syncthreads();
  }
  #pragma unroll
  for (int i = 0; i < 8; i++){
    int r = row0 + r0 + i;
    if (r < n){
      ushort4 a4, b4;
      a4.x = f2bf(acc[i][0]); a4.y = f2bf(acc[i][1]);
      a4.z = f2bf(acc[i][2]); a4.w = f2bf(acc[i][3]);
      b4.x = f2bf(acc[i][4]); b4.y = f2bf(acc[i][5]);
      b4.z = f2bf(acc[i][6]); b4.w = f2bf(acc[i][7]);
      *(ushort4*)(Hb + (size_t)r * 128 + c0)      = a4;
      *(ushort4*)(Hb + (size_t)r * 128 + c0 + 64) = b4;
    }
  }
}

// ---------------- att1: bf16 input ----------------
__global__ __launch_bounds__(256)
void att1_kernel(const unsigned short* __restrict__ Hb, const float* __restrict__ As,
                 const float* __restrict__ Ad, float* __restrict__ asrc,
                 float* __restrict__ adst, int n){
  __shared__ float sa[128], sd[128];
  int tid = threadIdx.x;
  if (tid < 128){ sa[tid] = As[tid]; sd[tid] = Ad[tid]; }
  __syncthreads();
  int t = blockIdx.x * 256 + tid;
  if (t >= n * 8) return;
  int node = t >> 3, h = t & 7;
  const uint4* hp = (const uint4*)(Hb + (size_t)node * 128 + h * 16);
  uint4 u0 = hp[0], u1 = hp[1];
  unsigned int w[8] = {u0.x,u0.y,u0.z,u0.w,u1.x,u1.y,u1.z,u1.w};
  float s = 0.f, d = 0.f;
  #pragma unroll
  for (int q = 0; q < 8; q++){
    float2 p = bfpair(w[q]);
    s = fmaf(p.x, sa[h*16 + 2*q],     s);
    s = fmaf(p.y, sa[h*16 + 2*q + 1], s);
    d = fmaf(p.x, sd[h*16 + 2*q],     d);
    d = fmaf(p.y, sd[h*16 + 2*q + 1], d);
  }
  asrc[t] = s; adst[t] = d;
}

// ---------------- agg1: wave per node, staged phase C ----------------
// Phase A: lane=(slot iA=lane>>3, head hA=lane&7); edge i=iA+k*8 in regs.
// Phase C: lane owns channel pair, head hB=lane>>3. Per 8-edge group:
//   (1) 8x readlane src + 8x bpermute ex, (2) 8x independent loads,
//   (3) unpack+fma. Inactive slots: sv=0, xv=0 (row-0 load, 0-weight fma).
__global__ __launch_bounds__(256)
void agg1_kernel(const unsigned short* __restrict__ Hb, const int* __restrict__ offs,
                 const int* __restrict__ cnt, const int* __restrict__ col,
                 const float* __restrict__ asrc, const float* __restrict__ adst,
                 const float* __restrict__ bias, float* __restrict__ G1, int n){
  int lane = threadIdx.x & 63;
  int wid  = threadIdx.x >> 6;
  int node = blockIdx.x * 4 + wid;
  if (node >= n) return;
  int beg = offs[node], deg = cnt[node];

  int hA = lane & 7, iA = lane >> 3;
  int hB = lane >> 3;
  float adA = adst[(unsigned)node * 8u + hA];
  const unsigned int* Hu = (const unsigned int*)Hb;

  float2 acc = make_float2(0.f, 0.f);
  float m_run = -INFINITY;
  float denomA = 0.f;   // per-lane partial (head hA)

  for (int c0 = 0; c0 < deg; c0 += 64){
    int cdeg = min(64, deg - c0);
    int sv[8]; float xv[8];
    float cm = -INFINITY;
    #pragma unroll
    for (int k = 0; k < 8; k++){
      int i = iA + k * 8;
      sv[k] = 0; xv[k] = -INFINITY;
      if (i < cdeg){
        int s = col[beg + c0 + i];
        sv[k] = s;
        float e = asrc[(unsigned)s * 8u + hA] + adA;
        e = e > 0.f ? e : 0.2f * e;
        xv[k] = e;
        cm = fmaxf(cm, e);
      }
    }
    cm = fmaxf(cm, __shfl_xor(cm, 8));
    cm = fmaxf(cm, __shfl_xor(cm, 16));
    cm = fmaxf(cm, __shfl_xor(cm, 32));
    float m_new = fmaxf(m_run, cm);
    float scaleA = __expf(m_run - m_new);   // first chunk: exp(-inf)=0
    denomA *= scaleA;
    #pragma unroll
    for (int k = 0; k < 8; k++){
      int i = iA + k * 8;
      if (i < cdeg){
        float ex = __expf(xv[k] - m_new);
        xv[k] = ex;
        denomA += ex;
      } else xv[k] = 0.f;
    }
    m_run = m_new;
    float scaleB = __shfl(scaleA, hB);
    acc.x *= scaleB; acc.y *= scaleB;
    // phase C: staged 8-edge groups
    #pragma unroll
    for (int k = 0; k < 8; k++){
      if (k * 8 >= cdeg) break;
      int sk[8]; float ek[8]; unsigned fu[8];
      #pragma unroll
      for (int j = 0; j < 8; j++){
        sk[j] = lane_bcast_i(sv[k], j * 8);       // uniform -> SGPR base
        ek[j] = __shfl(xv[k], j * 8 + hB);        // ds_bpermute
      }
      #pragma unroll
      for (int j = 0; j < 8; j++)
        fu[j] = Hu[(unsigned)sk[j] * 64u + lane]; // 8 independent loads
      #pragma unroll
      for (int j = 0; j < 8; j++){
        float2 f = bfpair(fu[j]);
        acc.x = fmaf(ek[j], f.x, acc.x);
        acc.y = fmaf(ek[j], f.y, acc.y);
      }
    }
  }
  denomA += __shfl_xor(denomA, 8);
  denomA += __shfl_xor(denomA, 16);
  denomA += __shfl_xor(denomA, 32);
  float denomB = __shfl(denomA, hB) + 1e-16f;
  float2 bv = ((const float2*)bias)[lane];
  float ox = acc.x / denomB + bv.x;
  float oy = acc.y / denomB + bv.y;
  ox = ox > 0.f ? ox : __expf(ox) - 1.f;   // ELU (x<0: cancellation benign)
  oy = oy > 0.f ? oy : __expf(oy) - 1.f;
  ((float2*)G1)[(size_t)node * 64 + lane] = make_float2(ox, oy);
}

// ---------------- GEMM2: [n,128]fp32 @ [128,40] -> bf16 ----------------
__global__ __launch_bounds__(256)
void gemm2_kernel(const float* __restrict__ X, const float* __restrict__ W,
                  unsigned short* __restrict__ Hb, int n){
  __shared__ float xs[16][132];
  __shared__ float ws[16][48];
  int tid = threadIdx.x;
  int rg = tid >> 3, cg = tid & 7;
  int r0 = rg * 4, c0 = cg * 6;
  int row0 = blockIdx.x * 128;
  float acc[4][6];
  #pragma unroll
  for (int i = 0; i < 4; i++)
    #pragma unroll
    for (int j = 0; j < 6; j++) acc[i][j] = 0.f;

  for (int k0 = 0; k0 < 128; k0 += 16){
    #pragma unroll
    for (int l = 0; l < 3; l++){
      int idx = tid + l * 256;
      int kk = idx / 48, c = idx % 48;
      ws[kk][c] = (c < 40) ? W[(size_t)(k0 + kk) * 40 + c] : 0.f;
    }
    #pragma unroll
    for (int l = 0; l < 2; l++){
      int f4 = tid + l * 256;
      int row = f4 >> 2, kq = f4 & 3;
      float4 v = make_float4(0.f, 0.f, 0.f, 0.f);
      if (row0 + row < n)
        v = *(const float4*)(X + (size_t)(row0 + row) * 128 + k0 + kq * 4);
      xs[kq*4+0][row] = v.x; xs[kq*4+1][row] = v.y;
      xs[kq*4+2][row] = v.z; xs[kq*4+3][row] = v.w;
    }
    __syncthreads();
    #pragma unroll
    for (int k = 0; k < 16; k++){
      float4 xa = *(const float4*)&xs[k][r0];
      float xr[4] = {xa.x, xa.y, xa.z, xa.w};
      float wr[6];
      #pragma unroll
      for (int j = 0; j < 6; j++) wr[j] = ws[k][c0 + j];
      #pragma unroll
      for (int i = 0; i < 4; i++)
        #pragma unroll
        for (int j = 0; j < 6; j++)
          acc[i][j] = fmaf(xr[i], wr[j], acc[i][j]);
    }
    __syncthreads();
  }
  #pragma unroll
  for (int i = 0; i < 4; i++){
    int r = row0 + r0 + i;
    if (r < n){
      #pragma unroll
      for (int j = 0; j < 6; j++){
        int c = c0 + j;
        if (c < 40) Hb[(size_t)r * 40 + c] = f2bf(acc[i][j]);
      }
    }
  }
}

// ---------------- att2: bf16 input ----------------
__global__ __launch_bounds__(256)
void att2_kernel(const unsigned short* __restrict__ Hb, const float* __restrict__ As,
                 const float* __restrict__ Ad, float* __restrict__ asrc,
                 float* __restrict__ adst, int n){
  int lane = threadIdx.x & 63;
  int node = blockIdx.x * 4 + (threadIdx.x >> 6);
  if (node >= n) return;
  float v = 0.f, a = 0.f, d = 0.f;
  if (lane < 40){
    v = bf2f(Hb[(size_t)node * 40 + lane]);
    a = As[lane];
    d = Ad[lane];
  }
  float s1 = wave_sum(v * a);
  float s2 = wave_sum(v * d);
  if (lane == 0){ asrc[node] = s1; adst[node] = s2; }
}

// ---------------- agg2 + bias + log_softmax, staged ----------------
__global__ __launch_bounds__(256)
void agg2_kernel(const unsigned short* __restrict__ Hb, const int* __restrict__ offs,
                 const int* __restrict__ cnt, const int* __restrict__ col,
                 const float* __restrict__ asrc, const float* __restrict__ adst,
                 const float* __restrict__ bias, float* __restrict__ out, int n){
  int lane = threadIdx.x & 63;
  int wid  = threadIdx.x >> 6;
  int node = blockIdx.x * 4 + wid;
  if (node >= n) return;
  int beg = offs[node], deg = cnt[node];
  float ad = adst[node];
  unsigned choff = (lane < 40) ? (unsigned)lane : 0u;  // clamped channel

  float acc = 0.f;
  float m_run = -INFINITY;
  float denom = 0.f;

  for (int c0 = 0; c0 < deg; c0 += 64){
    int cdeg = min(64, deg - c0);
    int s = 0; float ev = -INFINITY;
    if (lane < cdeg){
      s = col[beg + c0 + lane];
      float e = asrc[s] + ad;
      ev = e > 0.f ? e : 0.2f * e;
    }
    float cm = wave_max(ev);
    float m_new = fmaxf(m_run, cm);
    float scale = __expf(m_run - m_new);
    float ex = (lane < cdeg) ? __expf(ev - m_new) : 0.f;
    denom = denom * scale + wave_sum(ex);
    acc *= scale;
    m_run = m_new;
    // phase C: staged 8-edge groups
    #pragma unroll
    for (int kb = 0; kb < 8; kb++){
      if (kb * 8 >= cdeg) break;
      int sk[8]; float ek[8]; unsigned short fv[8];
      #pragma unroll
      for (int j = 0; j < 8; j++){
        int k = kb * 8 + j;
        sk[j] = lane_bcast_i(s, k);
        ek[j] = lane_bcast_f(ex, k);
      }
      #pragma unroll
      for (int j = 0; j < 8; j++)
        fv[j] = Hb[(unsigned)sk[j] * 40u + choff];  // 8 independent loads
      #pragma unroll
      for (int j = 0; j < 8; j++)
        acc = fmaf(ek[j], bf2f(fv[j]), acc);
    }
  }
  float val = 0.f;
  if (lane < 40) val = acc / (denom + 1e-16f) + bias[lane];

  float mx = wave_max(lane < 40 ? val : -INFINITY);
  float ssum = wave_sum(lane < 40 ? __expf(val - mx) : 0.f);
  float ls = logf(ssum);
  if (lane < 40) out[(size_t)node * 40 + lane] = val - mx - ls;
}

// ---------------- launch ----------------
extern "C" void kernel_launch(void* const* d_in, const int* in_sizes, int n_in,
                              void* d_out, int out_size, void* d_ws, size_t ws_size,
                              hipStream_t stream){
  const float* x   = (const float*)d_in[0];
  const int*   ei  = (const int*)d_in[1];
  const float* W1  = (const float*)d_in[2];
  const float* as1 = (const float*)d_in[3];
  const float* ad1 = (const float*)d_in[4];
  const float* b1  = (const float*)d_in[5];
  const float* W2  = (const float*)d_in[6];
  const float* as2 = (const float*)d_in[7];
  const float* ad2 = (const float*)d_in[8];
  const float* b2  = (const float*)d_in[9];
  float* out = (float*)d_out;

  int n = in_sizes[0] / 128;
  int E = in_sizes[1] / 2;
  const int* src = ei;
  const int* dst = ei + E;
  int tot = E + n;
  int nb = (n + NPB - 1) / NPB;       // buckets
  int nr = nb * G;                    // counter replicas

  char* w = (char*)d_ws;
  size_t off = 0;
  auto alloc = [&](size_t bytes){
    size_t r = off; off += (bytes + 255) & ~(size_t)255; return r;
  };
  int* bcnt = (int*)(w + alloc((size_t)nr * 4));
  unsigned int* bdata = (unsigned int*)(w + alloc((size_t)nr * RCAP * 4));
  int* offs = (int*)(w + alloc((size_t)n * 4));
  int* cnt  = (int*)(w + alloc((size_t)n * 4));
  int* col  = (int*)(w + alloc((size_t)nb * BSTRIDE * 4));
  unsigned short* h1b = (unsigned short*)(w + alloc((size_t)n * 128 * 2));
  float* g1   = (float*)(w + alloc((size_t)n * 128 * 4));
  float* s1   = (float*)(w + alloc((size_t)n * 8 * 4));
  float* t1   = (float*)(w + alloc((size_t)n * 8 * 4));
  unsigned short* h2b = h1b;   // layer-2 aliases (h1b dead after agg1)
  float* s2 = s1;
  float* t2 = t1;
  (void)ws_size; (void)n_in; (void)out_size;

  zero_bcnt_kernel<<<(nr + 255) / 256, 256, 0, stream>>>(bcnt, nr);
  binA_kernel<<<(tot + 255) / 256, 256, 0, stream>>>(src, dst, bcnt, bdata, E, tot);
  binB_kernel<<<nb, 256, 0, stream>>>(bcnt, bdata, offs, cnt, col, n);

  gemm1_kernel<<<(n + 127) / 128, 256, 0, stream>>>(x, W1, h1b, n);
  att1_kernel<<<(n * 8 + 255) / 256, 256, 0, stream>>>(h1b, as1, ad1, s1, t1, n);
  agg1_kernel<<<(n + 3) / 4, 256, 0, stream>>>(h1b, offs, cnt, col, s1, t1, b1, g1, n);

  gemm2_kernel<<<(n + 127) / 128, 256, 0, stream>>>(g1, W2, h2b, n);
  att2_kernel<<<(n + 3) / 4, 256, 0, stream>>>(h2b, as2, ad2, s2, t2, n);
  agg2_kernel<<<(n + 3) / 4, 256, 0, stream>>>(h2b, offs, cnt, col, s2, t2, b2, out, n);
}

// Round 10
// 465.526 us; speedup vs baseline: 1.8802x; 1.0217x over previous
//
#include <hip/hip_runtime.h>
#include <math.h>

// GAT 2-layer: N=100K nodes, E=1.6M edges + self loops.
// CSR build: bucketed binning, XCD-privatized counters (round 6).
// Round-10 change: binA processes 8 edges/thread with phase-split batching
//   (8 loads -> 8 independent atomicAdds -> 8 stores). Round-9 counters:
//   binA 108us, VALU 0.8%, 650GB/s -> one atomic in flight per thread,
//   pure latency serialization. Same MLP recipe that fixed agg1/agg2 (r8).
// Aggregation: wave per node, flash-style online softmax, register-scalarized
// staged phase C (rounds 7-8), bf16 feature gathers (round 4), fp32 accum.

#define NPB   32           // nodes per bucket (dst>>5)
#define G     8            // counter replicas (~per-XCD via blockIdx&7)
#define RCAP  192          // capacity per (bucket,replica)
#define BSTRIDE (G*RCAP)   // col entries per bucket
#define EPT   8            // edges per thread in binA

__device__ __forceinline__ float wave_max(float v){
  #pragma unroll
  for (int m = 1; m < 64; m <<= 1) v = fmaxf(v, __shfl_xor(v, m));
  return v;
}
__device__ __forceinline__ float wave_sum(float v){
  #pragma unroll
  for (int m = 1; m < 64; m <<= 1) v += __shfl_xor(v, m);
  return v;
}
__device__ __forceinline__ int lane_bcast_i(int v, int l){
  return __builtin_amdgcn_readlane(v, l);
}
__device__ __forceinline__ float lane_bcast_f(float v, int l){
  return __uint_as_float((unsigned)__builtin_amdgcn_readlane(__float_as_int(v), l));
}

// bf16 helpers (RNE pack, shift unpack)
__device__ __forceinline__ unsigned short f2bf(float f){
  unsigned int u = __float_as_uint(f);
  u += 0x7FFFu + ((u >> 16) & 1u);
  return (unsigned short)(u >> 16);
}
__device__ __forceinline__ float bf2f(unsigned short b){
  return __uint_as_float(((unsigned int)b) << 16);
}
__device__ __forceinline__ float2 bfpair(unsigned int u){
  float2 r;
  r.x = __uint_as_float(u << 16);
  r.y = __uint_as_float(u & 0xFFFF0000u);
  return r;
}

// ---------------- CSR build: bucketed binning ----------------

__global__ void zero_bcnt_kernel(int* __restrict__ p, int nr){
  int i = blockIdx.x * 256 + threadIdx.x;
  if (i < nr) p[i] = 0;
}

// pass A: 8 edges/thread; batch loads -> batch atomics -> batch stores.
__global__ void binA_kernel(const int* __restrict__ src, const int* __restrict__ dst,
                            int* __restrict__ bcnt, unsigned int* __restrict__ bdata,
                            int E, int tot){
  int base = blockIdx.x * (256 * EPT) + threadIdx.x;
  int rep = blockIdx.x & (G - 1);
  unsigned pk[EPT]; int rr[EPT]; int pos[EPT];
  #pragma unroll
  for (int k = 0; k < EPT; k++){
    int i = base + k * 256;
    rr[k] = -1; pk[k] = 0u;
    if (i < tot){
      int s, d;
      if (i < E){ s = src[i]; d = dst[i]; } else { s = i - E; d = s; }
      rr[k] = (d >> 5) * G + rep;
      pk[k] = (unsigned)s | ((unsigned)(d & 31) << 17);
    }
  }
  #pragma unroll
  for (int k = 0; k < EPT; k++)
    pos[k] = (rr[k] >= 0) ? atomicAdd(&bcnt[rr[k]], 1) : 0;
  #pragma unroll
  for (int k = 0; k < EPT; k++)
    if (rr[k] >= 0 && pos[k] < RCAP)
      bdata[(size_t)rr[k] * RCAP + pos[k]] = pk[k];
}

__global__ __launch_bounds__(256)
void binB_kernel(const int* __restrict__ bcnt, const unsigned int* __restrict__ bdata,
                 int* __restrict__ offs, int* __restrict__ cntg,
                 int* __restrict__ col, int n){
  __shared__ int hist[NPB];
  __shared__ int sc[NPB];
  __shared__ int curp[NPB];
  int tid = threadIdx.x;
  int b = blockIdx.x;
  int base_node = b * NPB;

  if (tid < NPB) hist[tid] = 0;
  __syncthreads();
  #pragma unroll
  for (int g = 0; g < G; g++){
    int rc = bcnt[b * G + g]; if (rc > RCAP) rc = RCAP;
    size_t rb = (size_t)(b * G + g) * RCAP;
    for (int j = tid; j < rc; j += 256)
      atomicAdd(&hist[bdata[rb + j] >> 17], 1);
  }
  __syncthreads();
  if (tid < NPB) sc[tid] = hist[tid];
  __syncthreads();
  #pragma unroll
  for (int d1 = 1; d1 < NPB; d1 <<= 1){
    int v = 0;
    if (tid < NPB && tid >= d1) v = sc[tid - d1];
    __syncthreads();
    if (tid < NPB) sc[tid] += v;
    __syncthreads();
  }
  if (tid < NPB){
    int ex = tid ? sc[tid - 1] : 0;
    int node = base_node + tid;
    if (node < n){
      offs[node] = b * BSTRIDE + ex;
      cntg[node] = hist[tid];
    }
    curp[tid] = ex;
  }
  __syncthreads();
  #pragma unroll
  for (int g = 0; g < G; g++){
    int rc = bcnt[b * G + g]; if (rc > RCAP) rc = RCAP;
    size_t rb = (size_t)(b * G + g) * RCAP;
    for (int j = tid; j < rc; j += 256){
      unsigned int u = bdata[rb + j];
      int r = atomicAdd(&curp[u >> 17], 1);
      col[b * BSTRIDE + r] = (int)(u & 0x1FFFFu);
    }
  }
}

// ---------------- GEMM1: [n,128]fp32 @ [128,128]fp32 -> bf16 ----------------
__global__ __launch_bounds__(256)
void gemm1_kernel(const float* __restrict__ X, const float* __restrict__ W,
                  unsigned short* __restrict__ Hb, int n){
  __shared__ float xs[16][132];
  __shared__ float ws[16][128];
  int tid = threadIdx.x;
  int rg = tid >> 4, cg = tid & 15;
  int r0 = rg * 8, c0 = cg * 4;
  int row0 = blockIdx.x * 128;
  float acc[8][8];
  #pragma unroll
  for (int i = 0; i < 8; i++)
    #pragma unroll
    for (int j = 0; j < 8; j++) acc[i][j] = 0.f;

  for (int k0 = 0; k0 < 128; k0 += 16){
    #pragma unroll
    for (int l = 0; l < 2; l++){
      int f4 = tid + l * 256;
      int kk = f4 >> 5, cq = f4 & 31;
      float4 w = *(const float4*)(W + (size_t)(k0 + kk) * 128 + cq * 4);
      *(float4*)&ws[kk][cq * 4] = w;
    }
    #pragma unroll
    for (int l = 0; l < 2; l++){
      int f4 = tid + l * 256;
      int row = f4 >> 2, kq = f4 & 3;
      float4 v = make_float4(0.f, 0.f, 0.f, 0.f);
      if (row0 + row < n)
        v = *(const float4*)(X + (size_t)(row0 + row) * 128 + k0 + kq * 4);
      xs[kq*4+0][row] = v.x; xs[kq*4+1][row] = v.y;
      xs[kq*4+2][row] = v.z; xs[kq*4+3][row] = v.w;
    }
    __syncthreads();
    #pragma unroll
    for (int k = 0; k < 16; k++){
      float4 xa = *(const float4*)&xs[k][r0];
      float4 xb = *(const float4*)&xs[k][r0 + 4];
      float4 wa = *(const float4*)&ws[k][c0];
      float4 wb = *(const float4*)&ws[k][c0 + 64];
      float xr[8] = {xa.x,xa.y,xa.z,xa.w,xb.x,xb.y,xb.z,xb.w};
      float wr[8] = {wa.x,wa.y,wa.z,wa.w,wb.x,wb.y,wb.z,wb.w};
      #pragma unroll
      for (int i = 0; i < 8; i++)
        #pragma unroll
        for (int j = 0; j < 8; j++)
          acc[i][j] = fmaf(xr[i], wr[j], acc[i][j]);
    }
    __syncthreads();
  }
  #pragma unroll
  for (int i = 0; i < 8; i++){
    int r = row0 + r0 + i;
    if (r < n){
      ushort4 a4, b4;
      a4.x = f2bf(acc[i][0]); a4.y = f2bf(acc[i][1]);
      a4.z = f2bf(acc[i][2]); a4.w = f2bf(acc[i][3]);
      b4.x = f2bf(acc[i][4]); b4.y = f2bf(acc[i][5]);
      b4.z = f2bf(acc[i][6]); b4.w = f2bf(acc[i][7]);
      *(ushort4*)(Hb + (size_t)r * 128 + c0)      = a4;
      *(ushort4*)(Hb + (size_t)r * 128 + c0 + 64) = b4;
    }
  }
}

// ---------------- att1: bf16 input ----------------
__global__ __launch_bounds__(256)
void att1_kernel(const unsigned short* __restrict__ Hb, const float* __restrict__ As,
                 const float* __restrict__ Ad, float* __restrict__ asrc,
                 float* __restrict__ adst, int n){
  __shared__ float sa[128], sd[128];
  int tid = threadIdx.x;
  if (tid < 128){ sa[tid] = As[tid]; sd[tid] = Ad[tid]; }
  __syncthreads();
  int t = blockIdx.x * 256 + tid;
  if (t >= n * 8) return;
  int node = t >> 3, h = t & 7;
  const uint4* hp = (const uint4*)(Hb + (size_t)node * 128 + h * 16);
  uint4 u0 = hp[0], u1 = hp[1];
  unsigned int w[8] = {u0.x,u0.y,u0.z,u0.w,u1.x,u1.y,u1.z,u1.w};
  float s = 0.f, d = 0.f;
  #pragma unroll
  for (int q = 0; q < 8; q++){
    float2 p = bfpair(w[q]);
    s = fmaf(p.x, sa[h*16 + 2*q],     s);
    s = fmaf(p.y, sa[h*16 + 2*q + 1], s);
    d = fmaf(p.x, sd[h*16 + 2*q],     d);
    d = fmaf(p.y, sd[h*16 + 2*q + 1], d);
  }
  asrc[t] = s; adst[t] = d;
}

// ---------------- agg1: wave per node, staged phase C ----------------
__global__ __launch_bounds__(256)
void agg1_kernel(const unsigned short* __restrict__ Hb, const int* __restrict__ offs,
                 const int* __restrict__ cnt, const int* __restrict__ col,
                 const float* __restrict__ asrc, const float* __restrict__ adst,
                 const float* __restrict__ bias, float* __restrict__ G1, int n){
  int lane = threadIdx.x & 63;
  int wid  = threadIdx.x >> 6;
  int node = blockIdx.x * 4 + wid;
  if (node >= n) return;
  int beg = offs[node], deg = cnt[node];

  int hA = lane & 7, iA = lane >> 3;
  int hB = lane >> 3;
  float adA = adst[(unsigned)node * 8u + hA];
  const unsigned int* Hu = (const unsigned int*)Hb;

  float2 acc = make_float2(0.f, 0.f);
  float m_run = -INFINITY;
  float denomA = 0.f;   // per-lane partial (head hA)

  for (int c0 = 0; c0 < deg; c0 += 64){
    int cdeg = min(64, deg - c0);
    int sv[8]; float xv[8];
    float cm = -INFINITY;
    #pragma unroll
    for (int k = 0; k < 8; k++){
      int i = iA + k * 8;
      sv[k] = 0; xv[k] = -INFINITY;
      if (i < cdeg){
        int s = col[beg + c0 + i];
        sv[k] = s;
        float e = asrc[(unsigned)s * 8u + hA] + adA;
        e = e > 0.f ? e : 0.2f * e;
        xv[k] = e;
        cm = fmaxf(cm, e);
      }
    }
    cm = fmaxf(cm, __shfl_xor(cm, 8));
    cm = fmaxf(cm, __shfl_xor(cm, 16));
    cm = fmaxf(cm, __shfl_xor(cm, 32));
    float m_new = fmaxf(m_run, cm);
    float scaleA = __expf(m_run - m_new);   // first chunk: exp(-inf)=0
    denomA *= scaleA;
    #pragma unroll
    for (int k = 0; k < 8; k++){
      int i = iA + k * 8;
      if (i < cdeg){
        float ex = __expf(xv[k] - m_new);
        xv[k] = ex;
        denomA += ex;
      } else xv[k] = 0.f;
    }
    m_run = m_new;
    float scaleB = __shfl(scaleA, hB);
    acc.x *= scaleB; acc.y *= scaleB;
    // phase C: staged 8-edge groups
    #pragma unroll
    for (int k = 0; k < 8; k++){
      if (k * 8 >= cdeg) break;
      int sk[8]; float ek[8]; unsigned fu[8];
      #pragma unroll
      for (int j = 0; j < 8; j++){
        sk[j] = lane_bcast_i(sv[k], j * 8);       // uniform -> SGPR base
        ek[j] = __shfl(xv[k], j * 8 + hB);        // ds_bpermute
      }
      #pragma unroll
      for (int j = 0; j < 8; j++)
        fu[j] = Hu[(unsigned)sk[j] * 64u + lane]; // 8 independent loads
      #pragma unroll
      for (int j = 0; j < 8; j++){
        float2 f = bfpair(fu[j]);
        acc.x = fmaf(ek[j], f.x, acc.x);
        acc.y = fmaf(ek[j], f.y, acc.y);
      }
    }
  }
  denomA += __shfl_xor(denomA, 8);
  denomA += __shfl_xor(denomA, 16);
  denomA += __shfl_xor(denomA, 32);
  float denomB = __shfl(denomA, hB) + 1e-16f;
  float2 bv = ((const float2*)bias)[lane];
  float ox = acc.x / denomB + bv.x;
  float oy = acc.y / denomB + bv.y;
  ox = ox > 0.f ? ox : __expf(ox) - 1.f;   // ELU (x<0: cancellation benign)
  oy = oy > 0.f ? oy : __expf(oy) - 1.f;
  ((float2*)G1)[(size_t)node * 64 + lane] = make_float2(ox, oy);
}

// ---------------- GEMM2: [n,128]fp32 @ [128,40] -> bf16 ----------------
__global__ __launch_bounds__(256)
void gemm2_kernel(const float* __restrict__ X, const float* __restrict__ W,
                  unsigned short* __restrict__ Hb, int n){
  __shared__ float xs[16][132];
  __shared__ float ws[16][48];
  int tid = threadIdx.x;
  int rg = tid >> 3, cg = tid & 7;
  int r0 = rg * 4, c0 = cg * 6;
  int row0 = blockIdx.x * 128;
  float acc[4][6];
  #pragma unroll
  for (int i = 0; i < 4; i++)
    #pragma unroll
    for (int j = 0; j < 6; j++) acc[i][j] = 0.f;

  for (int k0 = 0; k0 < 128; k0 += 16){
    #pragma unroll
    for (int l = 0; l < 3; l++){
      int idx = tid + l * 256;
      int kk = idx / 48, c = idx % 48;
      ws[kk][c] = (c < 40) ? W[(size_t)(k0 + kk) * 40 + c] : 0.f;
    }
    #pragma unroll
    for (int l = 0; l < 2; l++){
      int f4 = tid + l * 256;
      int row = f4 >> 2, kq = f4 & 3;
      float4 v = make_float4(0.f, 0.f, 0.f, 0.f);
      if (row0 + row < n)
        v = *(const float4*)(X + (size_t)(row0 + row) * 128 + k0 + kq * 4);
      xs[kq*4+0][row] = v.x; xs[kq*4+1][row] = v.y;
      xs[kq*4+2][row] = v.z; xs[kq*4+3][row] = v.w;
    }
    __syncthreads();
    #pragma unroll
    for (int k = 0; k < 16; k++){
      float4 xa = *(const float4*)&xs[k][r0];
      float xr[4] = {xa.x, xa.y, xa.z, xa.w};
      float wr[6];
      #pragma unroll
      for (int j = 0; j < 6; j++) wr[j] = ws[k][c0 + j];
      #pragma unroll
      for (int i = 0; i < 4; i++)
        #pragma unroll
        for (int j = 0; j < 6; j++)
          acc[i][j] = fmaf(xr[i], wr[j], acc[i][j]);
    }
    __syncthreads();
  }
  #pragma unroll
  for (int i = 0; i < 4; i++){
    int r = row0 + r0 + i;
    if (r < n){
      #pragma unroll
      for (int j = 0; j < 6; j++){
        int c = c0 + j;
        if (c < 40) Hb[(size_t)r * 40 + c] = f2bf(acc[i][j]);
      }
    }
  }
}

// ---------------- att2: bf16 input ----------------
__global__ __launch_bounds__(256)
void att2_kernel(const unsigned short* __restrict__ Hb, const float* __restrict__ As,
                 const float* __restrict__ Ad, float* __restrict__ asrc,
                 float* __restrict__ adst, int n){
  int lane = threadIdx.x & 63;
  int node = blockIdx.x * 4 + (threadIdx.x >> 6);
  if (node >= n) return;
  float v = 0.f, a = 0.f, d = 0.f;
  if (lane < 40){
    v = bf2f(Hb[(size_t)node * 40 + lane]);
    a = As[lane];
    d = Ad[lane];
  }
  float s1 = wave_sum(v * a);
  float s2 = wave_sum(v * d);
  if (lane == 0){ asrc[node] = s1; adst[node] = s2; }
}

// ---------------- agg2 + bias + log_softmax, staged ----------------
__global__ __launch_bounds__(256)
void agg2_kernel(const unsigned short* __restrict__ Hb, const int* __restrict__ offs,
                 const int* __restrict__ cnt, const int* __restrict__ col,
                 const float* __restrict__ asrc, const float* __restrict__ adst,
                 const float* __restrict__ bias, float* __restrict__ out, int n){
  int lane = threadIdx.x & 63;
  int wid  = threadIdx.x >> 6;
  int node = blockIdx.x * 4 + wid;
  if (node >= n) return;
  int beg = offs[node], deg = cnt[node];
  float ad = adst[node];
  unsigned choff = (lane < 40) ? (unsigned)lane : 0u;  // clamped channel

  float acc = 0.f;
  float m_run = -INFINITY;
  float denom = 0.f;

  for (int c0 = 0; c0 < deg; c0 += 64){
    int cdeg = min(64, deg - c0);
    int s = 0; float ev = -INFINITY;
    if (lane < cdeg){
      s = col[beg + c0 + lane];
      float e = asrc[s] + ad;
      ev = e > 0.f ? e : 0.2f * e;
    }
    float cm = wave_max(ev);
    float m_new = fmaxf(m_run, cm);
    float scale = __expf(m_run - m_new);
    float ex = (lane < cdeg) ? __expf(ev - m_new) : 0.f;
    denom = denom * scale + wave_sum(ex);
    acc *= scale;
    m_run = m_new;
    // phase C: staged 8-edge groups
    #pragma unroll
    for (int kb = 0; kb < 8; kb++){
      if (kb * 8 >= cdeg) break;
      int sk[8]; float ek[8]; unsigned short fv[8];
      #pragma unroll
      for (int j = 0; j < 8; j++){
        int k = kb * 8 + j;
        sk[j] = lane_bcast_i(s, k);
        ek[j] = lane_bcast_f(ex, k);
      }
      #pragma unroll
      for (int j = 0; j < 8; j++)
        fv[j] = Hb[(unsigned)sk[j] * 40u + choff];  // 8 independent loads
      #pragma unroll
      for (int j = 0; j < 8; j++)
        acc = fmaf(ek[j], bf2f(fv[j]), acc);
    }
  }
  float val = 0.f;
  if (lane < 40) val = acc / (denom + 1e-16f) + bias[lane];

  float mx = wave_max(lane < 40 ? val : -INFINITY);
  float ssum = wave_sum(lane < 40 ? __expf(val - mx) : 0.f);
  float ls = logf(ssum);
  if (lane < 40) out[(size_t)node * 40 + lane] = val - mx - ls;
}

// ---------------- launch ----------------
extern "C" void kernel_launch(void* const* d_in, const int* in_sizes, int n_in,
                              void* d_out, int out_size, void* d_ws, size_t ws_size,
                              hipStream_t stream){
  const float* x   = (const float*)d_in[0];
  const int*   ei  = (const int*)d_in[1];
  const float* W1  = (const float*)d_in[2];
  const float* as1 = (const float*)d_in[3];
  const float* ad1 = (const float*)d_in[4];
  const float* b1  = (const float*)d_in[5];
  const float* W2  = (const float*)d_in[6];
  const float* as2 = (const float*)d_in[7];
  const float* ad2 = (const float*)d_in[8];
  const float* b2  = (const float*)d_in[9];
  float* out = (float*)d_out;

  int n = in_sizes[0] / 128;
  int E = in_sizes[1] / 2;
  const int* src = ei;
  const int* dst = ei + E;
  int tot = E + n;
  int nb = (n + NPB - 1) / NPB;       // buckets
  int nr = nb * G;                    // counter replicas

  char* w = (char*)d_ws;
  size_t off = 0;
  auto alloc = [&](size_t bytes){
    size_t r = off; off += (bytes + 255) & ~(size_t)255; return r;
  };
  int* bcnt = (int*)(w + alloc((size_t)nr * 4));
  unsigned int* bdata = (unsigned int*)(w + alloc((size_t)nr * RCAP * 4));
  int* offs = (int*)(w + alloc((size_t)n * 4));
  int* cnt  = (int*)(w + alloc((size_t)n * 4));
  int* col  = (int*)(w + alloc((size_t)nb * BSTRIDE * 4));
  unsigned short* h1b = (unsigned short*)(w + alloc((size_t)n * 128 * 2));
  float* g1   = (float*)(w + alloc((size_t)n * 128 * 4));
  float* s1   = (float*)(w + alloc((size_t)n * 8 * 4));
  float* t1   = (float*)(w + alloc((size_t)n * 8 * 4));
  unsigned short* h2b = h1b;   // layer-2 aliases (h1b dead after agg1)
  float* s2 = s1;
  float* t2 = t1;
  (void)ws_size; (void)n_in; (void)out_size;

  zero_bcnt_kernel<<<(nr + 255) / 256, 256, 0, stream>>>(bcnt, nr);
  int nba = (tot + 256 * EPT - 1) / (256 * EPT);
  binA_kernel<<<nba, 256, 0, stream>>>(src, dst, bcnt, bdata, E, tot);
  binB_kernel<<<nb, 256, 0, stream>>>(bcnt, bdata, offs, cnt, col, n);

  gemm1_kernel<<<(n + 127) / 128, 256, 0, stream>>>(x, W1, h1b, n);
  att1_kernel<<<(n * 8 + 255) / 256, 256, 0, stream>>>(h1b, as1, ad1, s1, t1, n);
  agg1_kernel<<<(n + 3) / 4, 256, 0, stream>>>(h1b, offs, cnt, col, s1, t1, b1, g1, n);

  gemm2_kernel<<<(n + 127) / 128, 256, 0, stream>>>(g1, W2, h2b, n);
  att2_kernel<<<(n + 3) / 4, 256, 0, stream>>>(h2b, as2, ad2, s2, t2, n);
  agg2_kernel<<<(n + 3) / 4, 256, 0, stream>>>(h2b, offs, cnt, col, s2, t2, b2, out, n);
}

// Round 12
// 437.783 us; speedup vs baseline: 1.9994x; 1.0634x over previous
//
#include <hip/hip_runtime.h>
#include <math.h>

// GAT 2-layer: N=100K nodes, E=1.6M edges + self loops.
// Round-11 changes (resubmitted after infra timeout):
//  (a) bcnt/bdata layout [replica][bucket] (r = g*nb + b): round-10 showed
//      binA invariant to 8-deep atomic MLP (101us, VALU 1%) -> throughput
//      wall from LINE ping-pong: old layout put all 8 XCD replicas of a
//      bucket in one 64B line. New layout makes every counter line
//      XCD-exclusive (blockIdx&7 ~ XCD on round-robin dispatch).
//  (b) fused1 = binA (blocks < nba) || gemm1+att1-epilogue (blocks >= nba):
//      latency-idle binA blocks co-schedule with VALU-bound gemm1 blocks.
//  (c) att2 folded into gemm2 epilogue (8-lane shfl reduce).
// Aggregation: wave/node flash softmax, staged phase C (r7-8), bf16 gathers.

#define NPB   32           // nodes per bucket (dst>>5)
#define G     8            // counter replicas (~per-XCD via blockIdx&7)
#define RCAP  192          // capacity per (replica,bucket)
#define BSTRIDE (G*RCAP)   // col entries per bucket
#define EPT   8            // edges per thread in binA part

__device__ __forceinline__ float wave_max(float v){
  #pragma unroll
  for (int m = 1; m < 64; m <<= 1) v = fmaxf(v, __shfl_xor(v, m));
  return v;
}
__device__ __forceinline__ float wave_sum(float v){
  #pragma unroll
  for (int m = 1; m < 64; m <<= 1) v += __shfl_xor(v, m);
  return v;
}
__device__ __forceinline__ int lane_bcast_i(int v, int l){
  return __builtin_amdgcn_readlane(v, l);
}
__device__ __forceinline__ float lane_bcast_f(float v, int l){
  return __uint_as_float((unsigned)__builtin_amdgcn_readlane(__float_as_int(v), l));
}

// bf16 helpers (RNE pack, shift unpack)
__device__ __forceinline__ unsigned short f2bf(float f){
  unsigned int u = __float_as_uint(f);
  u += 0x7FFFu + ((u >> 16) & 1u);
  return (unsigned short)(u >> 16);
}
__device__ __forceinline__ float bf2f(unsigned short b){
  return __uint_as_float(((unsigned int)b) << 16);
}
__device__ __forceinline__ float2 bfpair(unsigned int u){
  float2 r;
  r.x = __uint_as_float(u << 16);
  r.y = __uint_as_float(u & 0xFFFF0000u);
  return r;
}

__global__ void zero_bcnt_kernel(int* __restrict__ p, int nr){
  int i = blockIdx.x * 256 + threadIdx.x;
  if (i < nr) p[i] = 0;
}

// ---------------- fused1: binA (blocks<nba) || gemm1+att1 ----------------
__global__ __launch_bounds__(256)
void fused1_kernel(const int* __restrict__ src, const int* __restrict__ dst,
                   int* __restrict__ bcnt, unsigned int* __restrict__ bdata,
                   int E, int tot, int nba, int nb,
                   const float* __restrict__ X, const float* __restrict__ W,
                   unsigned short* __restrict__ Hb,
                   const float* __restrict__ As, const float* __restrict__ Ad,
                   float* __restrict__ asrc, float* __restrict__ adst, int n){
  __shared__ float xs[16][132];
  __shared__ float ws[16][128];
  if ((int)blockIdx.x < nba){
    // ---- binA: 8 edges/thread, batched loads->atomics->stores ----
    int base = blockIdx.x * (256 * EPT) + threadIdx.x;
    int rep = blockIdx.x & (G - 1);
    unsigned pk[EPT]; int rr[EPT]; int pos[EPT];
    #pragma unroll
    for (int k = 0; k < EPT; k++){
      int i = base + k * 256;
      rr[k] = -1; pk[k] = 0u;
      if (i < tot){
        int s, d;
        if (i < E){ s = src[i]; d = dst[i]; } else { s = i - E; d = s; }
        rr[k] = rep * nb + (d >> 5);           // [replica][bucket]
        pk[k] = (unsigned)s | ((unsigned)(d & 31) << 17);
      }
    }
    #pragma unroll
    for (int k = 0; k < EPT; k++)
      pos[k] = (rr[k] >= 0) ? atomicAdd(&bcnt[rr[k]], 1) : 0;
    #pragma unroll
    for (int k = 0; k < EPT; k++)
      if (rr[k] >= 0 && pos[k] < RCAP)
        bdata[(size_t)rr[k] * RCAP + pos[k]] = pk[k];
    return;
  }
  // ---- gemm1: [n,128]@[128,128] -> bf16, + att1 epilogue ----
  int bid = blockIdx.x - nba;
  int tid = threadIdx.x;
  int rg = tid >> 4, cg = tid & 15;
  int r0 = rg * 8, c0 = cg * 4;
  int row0 = bid * 128;
  float acc[8][8];
  #pragma unroll
  for (int i = 0; i < 8; i++)
    #pragma unroll
    for (int j = 0; j < 8; j++) acc[i][j] = 0.f;

  for (int k0 = 0; k0 < 128; k0 += 16){
    #pragma unroll
    for (int l = 0; l < 2; l++){
      int f4 = tid + l * 256;
      int kk = f4 >> 5, cq = f4 & 31;
      float4 w = *(const float4*)(W + (size_t)(k0 + kk) * 128 + cq * 4);
      *(float4*)&ws[kk][cq * 4] = w;
    }
    #pragma unroll
    for (int l = 0; l < 2; l++){
      int f4 = tid + l * 256;
      int row = f4 >> 2, kq = f4 & 3;
      float4 v = make_float4(0.f, 0.f, 0.f, 0.f);
      if (row0 + row < n)
        v = *(const float4*)(X + (size_t)(row0 + row) * 128 + k0 + kq * 4);
      xs[kq*4+0][row] = v.x; xs[kq*4+1][row] = v.y;
      xs[kq*4+2][row] = v.z; xs[kq*4+3][row] = v.w;
    }
    __syncthreads();
    #pragma unroll
    for (int k = 0; k < 16; k++){
      float4 xa = *(const float4*)&xs[k][r0];
      float4 xb = *(const float4*)&xs[k][r0 + 4];
      float4 wa = *(const float4*)&ws[k][c0];
      float4 wb = *(const float4*)&ws[k][c0 + 64];
      float xr[8] = {xa.x,xa.y,xa.z,xa.w,xb.x,xb.y,xb.z,xb.w};
      float wr[8] = {wa.x,wa.y,wa.z,wa.w,wb.x,wb.y,wb.z,wb.w};
      #pragma unroll
      for (int i = 0; i < 8; i++)
        #pragma unroll
        for (int j = 0; j < 8; j++)
          acc[i][j] = fmaf(xr[i], wr[j], acc[i][j]);
    }
    __syncthreads();
  }
  // store bf16 h1
  #pragma unroll
  for (int i = 0; i < 8; i++){
    int r = row0 + r0 + i;
    if (r < n){
      ushort4 a4, b4;
      a4.x = f2bf(acc[i][0]); a4.y = f2bf(acc[i][1]);
      a4.z = f2bf(acc[i][2]); a4.w = f2bf(acc[i][3]);
      b4.x = f2bf(acc[i][4]); b4.y = f2bf(acc[i][5]);
      b4.z = f2bf(acc[i][6]); b4.w = f2bf(acc[i][7]);
      *(ushort4*)(Hb + (size_t)r * 128 + c0)      = a4;
      *(ushort4*)(Hb + (size_t)r * 128 + c0 + 64) = b4;
    }
  }
  // att1 epilogue: thread holds cols 4cg..4cg+3 (head cg>>2) and
  // 64+4cg..64+4cg+3 (head 4+(cg>>2)); reduce over lanes cg&3 (4-aligned).
  float4 a0 = *(const float4*)(As + cg * 4);
  float4 a1 = *(const float4*)(As + 64 + cg * 4);
  float4 d0 = *(const float4*)(Ad + cg * 4);
  float4 d1 = *(const float4*)(Ad + 64 + cg * 4);
  int hL = cg >> 2, hH = 4 + (cg >> 2);
  #pragma unroll
  for (int i = 0; i < 8; i++){
    int r = row0 + r0 + i;
    float sL = acc[i][0]*a0.x + acc[i][1]*a0.y + acc[i][2]*a0.z + acc[i][3]*a0.w;
    float sH = acc[i][4]*a1.x + acc[i][5]*a1.y + acc[i][6]*a1.z + acc[i][7]*a1.w;
    float tL = acc[i][0]*d0.x + acc[i][1]*d0.y + acc[i][2]*d0.z + acc[i][3]*d0.w;
    float tH = acc[i][4]*d1.x + acc[i][5]*d1.y + acc[i][6]*d1.z + acc[i][7]*d1.w;
    sL += __shfl_xor(sL, 1); sL += __shfl_xor(sL, 2);
    sH += __shfl_xor(sH, 1); sH += __shfl_xor(sH, 2);
    tL += __shfl_xor(tL, 1); tL += __shfl_xor(tL, 2);
    tH += __shfl_xor(tH, 1); tH += __shfl_xor(tH, 2);
    if ((cg & 3) == 0 && r < n){
      asrc[r * 8 + hL] = sL; asrc[r * 8 + hH] = sH;
      adst[r * 8 + hL] = tL; adst[r * 8 + hH] = tH;
    }
  }
}

// ---------------- binB: merge replicas -> per-bucket CSR ----------------
__global__ __launch_bounds__(256)
void binB_kernel(const int* __restrict__ bcnt, const unsigned int* __restrict__ bdata,
                 int* __restrict__ offs, int* __restrict__ cntg,
                 int* __restrict__ col, int n, int nb){
  __shared__ int hist[NPB];
  __shared__ int sc[NPB];
  __shared__ int curp[NPB];
  int tid = threadIdx.x;
  int b = blockIdx.x;
  int base_node = b * NPB;

  if (tid < NPB) hist[tid] = 0;
  __syncthreads();
  #pragma unroll
  for (int g = 0; g < G; g++){
    int rc = bcnt[g * nb + b]; if (rc > RCAP) rc = RCAP;
    size_t rb = (size_t)(g * nb + b) * RCAP;
    for (int j = tid; j < rc; j += 256)
      atomicAdd(&hist[bdata[rb + j] >> 17], 1);
  }
  __syncthreads();
  if (tid < NPB) sc[tid] = hist[tid];
  __syncthreads();
  #pragma unroll
  for (int d1 = 1; d1 < NPB; d1 <<= 1){
    int v = 0;
    if (tid < NPB && tid >= d1) v = sc[tid - d1];
    __syncthreads();
    if (tid < NPB) sc[tid] += v;
    __syncthreads();
  }
  if (tid < NPB){
    int ex = tid ? sc[tid - 1] : 0;
    int node = base_node + tid;
    if (node < n){
      offs[node] = b * BSTRIDE + ex;
      cntg[node] = hist[tid];
    }
    curp[tid] = ex;
  }
  __syncthreads();
  #pragma unroll
  for (int g = 0; g < G; g++){
    int rc = bcnt[g * nb + b]; if (rc > RCAP) rc = RCAP;
    size_t rb = (size_t)(g * nb + b) * RCAP;
    for (int j = tid; j < rc; j += 256){
      unsigned int u = bdata[rb + j];
      int r = atomicAdd(&curp[u >> 17], 1);
      col[b * BSTRIDE + r] = (int)(u & 0x1FFFFu);
    }
  }
}

// ---------------- agg1: wave per node, staged phase C ----------------
__global__ __launch_bounds__(256)
void agg1_kernel(const unsigned short* __restrict__ Hb, const int* __restrict__ offs,
                 const int* __restrict__ cnt, const int* __restrict__ col,
                 const float* __restrict__ asrc, const float* __restrict__ adst,
                 const float* __restrict__ bias, float* __restrict__ G1, int n){
  int lane = threadIdx.x & 63;
  int wid  = threadIdx.x >> 6;
  int node = blockIdx.x * 4 + wid;
  if (node >= n) return;
  int beg = offs[node], deg = cnt[node];

  int hA = lane & 7, iA = lane >> 3;
  int hB = lane >> 3;
  float adA = adst[(unsigned)node * 8u + hA];
  const unsigned int* Hu = (const unsigned int*)Hb;

  float2 acc = make_float2(0.f, 0.f);
  float m_run = -INFINITY;
  float denomA = 0.f;   // per-lane partial (head hA)

  for (int c0 = 0; c0 < deg; c0 += 64){
    int cdeg = min(64, deg - c0);
    int sv[8]; float xv[8];
    float cm = -INFINITY;
    #pragma unroll
    for (int k = 0; k < 8; k++){
      int i = iA + k * 8;
      sv[k] = 0; xv[k] = -INFINITY;
      if (i < cdeg){
        int s = col[beg + c0 + i];
        sv[k] = s;
        float e = asrc[(unsigned)s * 8u + hA] + adA;
        e = e > 0.f ? e : 0.2f * e;
        xv[k] = e;
        cm = fmaxf(cm, e);
      }
    }
    cm = fmaxf(cm, __shfl_xor(cm, 8));
    cm = fmaxf(cm, __shfl_xor(cm, 16));
    cm = fmaxf(cm, __shfl_xor(cm, 32));
    float m_new = fmaxf(m_run, cm);
    float scaleA = __expf(m_run - m_new);   // first chunk: exp(-inf)=0
    denomA *= scaleA;
    #pragma unroll
    for (int k = 0; k < 8; k++){
      int i = iA + k * 8;
      if (i < cdeg){
        float ex = __expf(xv[k] - m_new);
        xv[k] = ex;
        denomA += ex;
      } else xv[k] = 0.f;
    }
    m_run = m_new;
    float scaleB = __shfl(scaleA, hB);
    acc.x *= scaleB; acc.y *= scaleB;
    // phase C: staged 8-edge groups
    #pragma unroll
    for (int k = 0; k < 8; k++){
      if (k * 8 >= cdeg) break;
      int sk[8]; float ek[8]; unsigned fu[8];
      #pragma unroll
      for (int j = 0; j < 8; j++){
        sk[j] = lane_bcast_i(sv[k], j * 8);       // uniform -> SGPR base
        ek[j] = __shfl(xv[k], j * 8 + hB);        // ds_bpermute
      }
      #pragma unroll
      for (int j = 0; j < 8; j++)
        fu[j] = Hu[(unsigned)sk[j] * 64u + lane]; // 8 independent loads
      #pragma unroll
      for (int j = 0; j < 8; j++){
        float2 f = bfpair(fu[j]);
        acc.x = fmaf(ek[j], f.x, acc.x);
        acc.y = fmaf(ek[j], f.y, acc.y);
      }
    }
  }
  denomA += __shfl_xor(denomA, 8);
  denomA += __shfl_xor(denomA, 16);
  denomA += __shfl_xor(denomA, 32);
  float denomB = __shfl(denomA, hB) + 1e-16f;
  float2 bv = ((const float2*)bias)[lane];
  float ox = acc.x / denomB + bv.x;
  float oy = acc.y / denomB + bv.y;
  ox = ox > 0.f ? ox : __expf(ox) - 1.f;   // ELU
  oy = oy > 0.f ? oy : __expf(oy) - 1.f;
  ((float2*)G1)[(size_t)node * 64 + lane] = make_float2(ox, oy);
}

// ---------------- gemm2: [n,128]@[128,40] -> bf16, + att2 epilogue ----------
__global__ __launch_bounds__(256)
void gemm2_kernel(const float* __restrict__ X, const float* __restrict__ W,
                  unsigned short* __restrict__ Hb,
                  const float* __restrict__ As2, const float* __restrict__ Ad2,
                  float* __restrict__ asrc2, float* __restrict__ adst2, int n){
  __shared__ float xs[16][132];
  __shared__ float ws[16][48];
  int tid = threadIdx.x;
  int rg = tid >> 3, cg = tid & 7;
  int r0 = rg * 4, c0 = cg * 6;
  int row0 = blockIdx.x * 128;
  float acc[4][6];
  #pragma unroll
  for (int i = 0; i < 4; i++)
    #pragma unroll
    for (int j = 0; j < 6; j++) acc[i][j] = 0.f;

  for (int k0 = 0; k0 < 128; k0 += 16){
    #pragma unroll
    for (int l = 0; l < 3; l++){
      int idx = tid + l * 256;
      int kk = idx / 48, c = idx % 48;
      ws[kk][c] = (c < 40) ? W[(size_t)(k0 + kk) * 40 + c] : 0.f;
    }
    #pragma unroll
    for (int l = 0; l < 2; l++){
      int f4 = tid + l * 256;
      int row = f4 >> 2, kq = f4 & 3;
      float4 v = make_float4(0.f, 0.f, 0.f, 0.f);
      if (row0 + row < n)
        v = *(const float4*)(X + (size_t)(row0 + row) * 128 + k0 + kq * 4);
      xs[kq*4+0][row] = v.x; xs[kq*4+1][row] = v.y;
      xs[kq*4+2][row] = v.z; xs[kq*4+3][row] = v.w;
    }
    __syncthreads();
    #pragma unroll
    for (int k = 0; k < 16; k++){
      float4 xa = *(const float4*)&xs[k][r0];
      float xr[4] = {xa.x, xa.y, xa.z, xa.w};
      float wr[6];
      #pragma unroll
      for (int j = 0; j < 6; j++) wr[j] = ws[k][c0 + j];
      #pragma unroll
      for (int i = 0; i < 4; i++)
        #pragma unroll
        for (int j = 0; j < 6; j++)
          acc[i][j] = fmaf(xr[i], wr[j], acc[i][j]);
    }
    __syncthreads();
  }
  #pragma unroll
  for (int i = 0; i < 4; i++){
    int r = row0 + r0 + i;
    if (r < n){
      #pragma unroll
      for (int j = 0; j < 6; j++){
        int c = c0 + j;
        if (c < 40) Hb[(size_t)r * 40 + c] = f2bf(acc[i][j]);
      }
    }
  }
  // att2 epilogue: reduce over the 8 lanes (cg) of each row group.
  float av[6], dv[6];
  #pragma unroll
  for (int j = 0; j < 6; j++){
    int c = c0 + j;
    av[j] = (c < 40) ? As2[c] : 0.f;
    dv[j] = (c < 40) ? Ad2[c] : 0.f;
  }
  #pragma unroll
  for (int i = 0; i < 4; i++){
    int r = row0 + r0 + i;
    float s = 0.f, t = 0.f;
    #pragma unroll
    for (int j = 0; j < 6; j++){
      s = fmaf(acc[i][j], av[j], s);
      t = fmaf(acc[i][j], dv[j], t);
    }
    s += __shfl_xor(s, 1); s += __shfl_xor(s, 2); s += __shfl_xor(s, 4);
    t += __shfl_xor(t, 1); t += __shfl_xor(t, 2); t += __shfl_xor(t, 4);
    if (cg == 0 && r < n){ asrc2[r] = s; adst2[r] = t; }
  }
}

// ---------------- agg2 + bias + log_softmax, staged ----------------
__global__ __launch_bounds__(256)
void agg2_kernel(const unsigned short* __restrict__ Hb, const int* __restrict__ offs,
                 const int* __restrict__ cnt, const int* __restrict__ col,
                 const float* __restrict__ asrc, const float* __restrict__ adst,
                 const float* __restrict__ bias, float* __restrict__ out, int n){
  int lane = threadIdx.x & 63;
  int wid  = threadIdx.x >> 6;
  int node = blockIdx.x * 4 + wid;
  if (node >= n) return;
  int beg = offs[node], deg = cnt[node];
  float ad = adst[node];
  unsigned choff = (lane < 40) ? (unsigned)lane : 0u;

  float acc = 0.f;
  float m_run = -INFINITY;
  float denom = 0.f;

  for (int c0 = 0; c0 < deg; c0 += 64){
    int cdeg = min(64, deg - c0);
    int s = 0; float ev = -INFINITY;
    if (lane < cdeg){
      s = col[beg + c0 + lane];
      float e = asrc[s] + ad;
      ev = e > 0.f ? e : 0.2f * e;
    }
    float cm = wave_max(ev);
    float m_new = fmaxf(m_run, cm);
    float scale = __expf(m_run - m_new);
    float ex = (lane < cdeg) ? __expf(ev - m_new) : 0.f;
    denom = denom * scale + wave_sum(ex);
    acc *= scale;
    m_run = m_new;
    #pragma unroll
    for (int kb = 0; kb < 8; kb++){
      if (kb * 8 >= cdeg) break;
      int sk[8]; float ek[8]; unsigned short fv[8];
      #pragma unroll
      for (int j = 0; j < 8; j++){
        int k = kb * 8 + j;
        sk[j] = lane_bcast_i(s, k);
        ek[j] = lane_bcast_f(ex, k);
      }
      #pragma unroll
      for (int j = 0; j < 8; j++)
        fv[j] = Hb[(unsigned)sk[j] * 40u + choff];
      #pragma unroll
      for (int j = 0; j < 8; j++)
        acc = fmaf(ek[j], bf2f(fv[j]), acc);
    }
  }
  float val = 0.f;
  if (lane < 40) val = acc / (denom + 1e-16f) + bias[lane];

  float mx = wave_max(lane < 40 ? val : -INFINITY);
  float ssum = wave_sum(lane < 40 ? __expf(val - mx) : 0.f);
  float ls = logf(ssum);
  if (lane < 40) out[(size_t)node * 40 + lane] = val - mx - ls;
}

// ---------------- launch ----------------
extern "C" void kernel_launch(void* const* d_in, const int* in_sizes, int n_in,
                              void* d_out, int out_size, void* d_ws, size_t ws_size,
                              hipStream_t stream){
  const float* x   = (const float*)d_in[0];
  const int*   ei  = (const int*)d_in[1];
  const float* W1  = (const float*)d_in[2];
  const float* as1 = (const float*)d_in[3];
  const float* ad1 = (const float*)d_in[4];
  const float* b1  = (const float*)d_in[5];
  const float* W2  = (const float*)d_in[6];
  const float* as2 = (const float*)d_in[7];
  const float* ad2 = (const float*)d_in[8];
  const float* b2  = (const float*)d_in[9];
  float* out = (float*)d_out;

  int n = in_sizes[0] / 128;
  int E = in_sizes[1] / 2;
  const int* src = ei;
  const int* dst = ei + E;
  int tot = E + n;
  int nb = (n + NPB - 1) / NPB;       // buckets
  int nr = nb * G;                    // counter replicas

  char* w = (char*)d_ws;
  size_t off = 0;
  auto alloc = [&](size_t bytes){
    size_t r = off; off += (bytes + 255) & ~(size_t)255; return r;
  };
  int* bcnt = (int*)(w + alloc((size_t)nr * 4));
  unsigned int* bdata = (unsigned int*)(w + alloc((size_t)nr * RCAP * 4));
  int* offs = (int*)(w + alloc((size_t)n * 4));
  int* cnt  = (int*)(w + alloc((size_t)n * 4));
  int* col  = (int*)(w + alloc((size_t)nb * BSTRIDE * 4));
  unsigned short* h1b = (unsigned short*)(w + alloc((size_t)n * 128 * 2));
  float* g1   = (float*)(w + alloc((size_t)n * 128 * 4));
  float* s1   = (float*)(w + alloc((size_t)n * 8 * 4));
  float* t1   = (float*)(w + alloc((size_t)n * 8 * 4));
  unsigned short* h2b = h1b;   // layer-2 aliases (h1b dead after agg1)
  float* s2 = s1;
  float* t2 = t1;
  (void)ws_size; (void)n_in; (void)out_size;

  zero_bcnt_kernel<<<(nr + 255) / 256, 256, 0, stream>>>(bcnt, nr);
  int nba = (tot + 256 * EPT - 1) / (256 * EPT);
  int ngm = (n + 127) / 128;
  fused1_kernel<<<nba + ngm, 256, 0, stream>>>(src, dst, bcnt, bdata, E, tot,
                                               nba, nb, x, W1, h1b,
                                               as1, ad1, s1, t1, n);
  binB_kernel<<<nb, 256, 0, stream>>>(bcnt, bdata, offs, cnt, col, n, nb);

  agg1_kernel<<<(n + 3) / 4, 256, 0, stream>>>(h1b, offs, cnt, col, s1, t1, b1, g1, n);

  gemm2_kernel<<<ngm, 256, 0, stream>>>(g1, W2, h2b, as2, ad2, s2, t2, n);
  agg2_kernel<<<(n + 3) / 4, 256, 0, stream>>>(h2b, offs, cnt, col, s2, t2, b2, out, n);
}